// Round 1
// baseline (943.546 us; speedup 1.0000x reference)
//
#include <hip/hip_runtime.h>
#include <math.h>

// SwigluMoE routed, round 5: 5-dispatch pipeline.
//   memset(tok,cnt) -> prep(gate + x->bf16 + w1->bf16) -> fc1(+w2-cvt riders)
//   -> fc2 -> combine
// R5 changes vs R4 (prep was latency-bound at 1.9 TB/s, 23% peak):
//   * cvt inner body widened to 32 floats/iter (8x float4 in flight per lane)
//   * nontemporal loads on f32 weights (read-once; keeps bf16 w1b L3-resident
//     for fc1's repeated B-tile reads)
//   * w2 conversion moved OFF prep's critical path into the fc1 dispatch as
//     2048 memory-only rider blocks (blockIdx.x >= 32); hides under fc1 MFMA
//     (fc1 had ~0.8 TB/s HBM use, MfmaUtil 37% -> big memory headroom).
// fc1/fc2: m97-style global_load_lds BK=64 bf16 MFMA (unchanged this round).
// T=4096, H=2048, I=2048 (2I=4096), E=8, top-2. Routed = 206 GFLOP.

#define T_TOK 4096
#define H_DIM 2048
#define I_DIM 2048
#define F_DIM 4096   // 2*I
#define E_NUM 8
#define ALPHA_C 1.702f
#define ALPHA_LOG2E 2.4554674f   // 1.702 * log2(e)

// fp32 fallback tiling
#define TILE_M 64
#define KT 32
#define ACT_CAP_F (2 * T_TOK + E_NUM * TILE_M)   // 8704
// bf16 path tiling
#define BTM 128
#define ACT_CAP_B (2 * T_TOK + E_NUM * BTM)      // 9216

#define GATE_BLOCKS (T_TOK / 4)   // 1024
#define CVT_BLOCKS  4096          // w1 cvt: 4096*256 threads, 2 quads each
#define N1Q 2097152               // w1 floats / 32  (8*4096*2048/32)
#define N2Q 1048576               // w2 floats / 32  (8*2048*2048/32)
#define W2X 8                     // rider columns in fc1 grid (8*256 blocks)

typedef unsigned short ushort_t;
typedef __attribute__((ext_vector_type(8))) unsigned short ushort8v;
typedef __attribute__((ext_vector_type(8))) __bf16 bf16x8;
typedef __attribute__((ext_vector_type(4))) float f32x4;

__device__ __forceinline__ ushort_t f2bf(float f) {
    unsigned int u = __float_as_uint(f);
    unsigned int r = (u + 0x7FFFu + ((u >> 16) & 1u)) >> 16;  // RNE
    return (ushort_t)r;
}
__device__ __forceinline__ float bf2f(ushort_t b) {
    return __uint_as_float(((unsigned int)b) << 16);
}

__device__ __forceinline__ void gl_lds16(const ushort_t* g, ushort_t* l) {
    __builtin_amdgcn_global_load_lds(
        (const __attribute__((address_space(1))) void*)g,
        (__attribute__((address_space(3))) void*)l, 16, 0, 0);
}

// convert 32 consecutive floats -> 32 bf16. 8 nontemporal float4 loads issued
// back-to-back (128 B/lane in flight), 4x ushort8 stores (cached: bf16 copy
// is re-read by fc1/fc2, keep it in L3).
__device__ __forceinline__ void cvt32(const float* __restrict__ s,
                                      ushort_t* __restrict__ d) {
    f32x4 v[8];
#pragma unroll
    for (int j = 0; j < 8; j++)
        v[j] = __builtin_nontemporal_load((const f32x4*)(s + 4 * j));
#pragma unroll
    for (int g = 0; g < 4; g++) {
        ushort8v o;
#pragma unroll
        for (int k = 0; k < 8; k++)
            o[k] = f2bf(v[2 * g + (k >> 2)][k & 3]);
        *(ushort8v*)(d + 8 * g) = o;
    }
}

// ---------------------------------------------------------------- prep ------
// blocks [0, GATE_BLOCKS): gating (4 tokens/block, 1 wave each) + x->bf16.
// blocks [GATE_BLOCKS, +CVT_BLOCKS): w1 -> bf16, 32 floats/iter, exact trip.
__global__ __launch_bounds__(256) void prep_kernel(
    const float* __restrict__ x, const float* __restrict__ gw,
    const float* __restrict__ w1, ushort_t* __restrict__ wb,
    ushort_t* __restrict__ xb, int* __restrict__ tok, int4* __restrict__ tidx,
    float2* __restrict__ twgt, int* __restrict__ cnt) {
    if (blockIdx.x < GATE_BLOCKS) {
        int t = blockIdx.x * 4 + (threadIdx.x >> 6);
        int lane = threadIdx.x & 63;
        const float* xr = x + (size_t)t * H_DIM;
        ushort_t* xbr = xb + (size_t)t * H_DIM;
        float acc[E_NUM];
#pragma unroll
        for (int e = 0; e < E_NUM; e++) acc[e] = 0.f;
#pragma unroll
        for (int i = 0; i < H_DIM / 256; i++) {
            int j = (i * 64 + lane) * 4;
            float4 xv = *(const float4*)(xr + j);
            *(ushort4*)(xbr + j) =
                make_ushort4(f2bf(xv.x), f2bf(xv.y), f2bf(xv.z), f2bf(xv.w));
#pragma unroll
            for (int e = 0; e < E_NUM; e++) {
                float4 g = *(const float4*)(gw + e * H_DIM + j);
                acc[e] += xv.x * g.x + xv.y * g.y + xv.z * g.z + xv.w * g.w;
            }
        }
#pragma unroll
        for (int e = 0; e < E_NUM; e++) {
#pragma unroll
            for (int s = 32; s > 0; s >>= 1) acc[e] += __shfl_xor(acc[e], s, 64);
        }
        if (lane == 0) {
            int i0 = 0; float b0 = acc[0];
            for (int e = 1; e < E_NUM; e++) if (acc[e] > b0) { b0 = acc[e]; i0 = e; }
            int i1 = -1; float b1 = -3.0e38f;
            for (int e = 0; e < E_NUM; e++) {
                if (e == i0) continue;
                if (acc[e] > b1) { b1 = acc[e]; i1 = e; }
            }
            float e10 = expf(b1 - b0);
            float w0 = 1.f / (1.f + e10);
            float w1v = 1.f - w0;
            int p0 = atomicAdd(&cnt[i0], 1);
            tok[i0 * T_TOK + p0] = t;
            int p1 = atomicAdd(&cnt[i1], 1);
            tok[i1 * T_TOK + p1] = t;
            tidx[t] = make_int4(i0, p0, i1, p1);
            twgt[t] = make_float2(w0, w1v);
        }
    } else {
        int idx = (int)(blockIdx.x - GATE_BLOCKS) * 256 + (int)threadIdx.x;
        const int stride = CVT_BLOCKS * 256;
        for (int q = idx; q < N1Q; q += stride)
            cvt32(w1 + (size_t)q * 32, wb + (size_t)q * 32);
    }
}

// helper: padded count prefix from cnt[] (8 L2-hot loads, wave-uniform)
__device__ __forceinline__ void calc_off(const int* __restrict__ cnt, int e,
                                         int& off_e, int& cpad_e) {
    int o = 0, cp = 0;
#pragma unroll
    for (int q = 0; q < E_NUM; q++) {
        int c = (cnt[q] + BTM - 1) & ~(BTM - 1);
        if (q < e) o += c;
        if (q == e) cp = c;
    }
    off_e = o; cpad_e = cp;
}

// ============================ bf16 MFMA path ================================
// fc1: 128 pair-rows x 64 i (=128 f rows, g/l split tiles). BK=64 as two
// 32-wide sub-tiles (64B row stride: 2-way LDS aliasing free; keeps
// global_load_lds contiguous-lane layout). 4 waves, 2x2.
// blockIdx.x >= 32: w2->bf16 rider blocks (memory-only, overlap with MFMA).
__global__ __launch_bounds__(256, 3) void fc1_mfma(
    const ushort_t* __restrict__ xb, const ushort_t* __restrict__ w1b,
    const float* __restrict__ b1, const int* __restrict__ tok,
    const int* __restrict__ cnt, ushort_t* __restrict__ act,
    const float* __restrict__ w2f, ushort_t* __restrict__ w2b) {
    if (blockIdx.x >= I_DIM / 64) {
        // w2 conversion rider: 2048 blocks, 2 quads/thread, exact trip.
        int flat = (int)(blockIdx.x - I_DIM / 64) * 256 + (int)blockIdx.y;
        int idx = flat * 256 + (int)threadIdx.x;
        const int stride = W2X * 256 * 256;
        for (int q = idx; q < N2Q; q += stride)
            cvt32(w2f + (size_t)q * 32, w2b + (size_t)q * 32);
        return;
    }
    int e = blockIdx.y >> 5;
    int tile = blockIdx.y & 31;
    int off_e, cpad_e;
    calc_off(cnt, e, off_e, cpad_e);
    if (tile * BTM >= cpad_e) return;
    int i0 = blockIdx.x * 64;

    __shared__ ushort_t As[2][128 * 32];
    __shared__ ushort_t Bg[2][64 * 32];
    __shared__ ushort_t Bl[2][64 * 32];

    int tid = threadIdx.x;
    int lane = tid & 63;
    int ww = tid >> 6;
    int wm = ww & 1, wn = ww >> 1;
    int l15 = lane & 15, quad = lane >> 4;
    int r4 = lane >> 2;           // 0..15
    int koff = (lane & 3) * 8;    // 0,8,16,24

    const int* tlist = tok + e * T_TOK + tile * BTM;
    int ar0 = ww * 32 + r4;
    const ushort_t* a0 = xb + (size_t)tlist[ar0] * H_DIM + koff;
    const ushort_t* a1 = xb + (size_t)tlist[ar0 + 16] * H_DIM + koff;
    int il = ww * 16 + r4;
    const ushort_t* bsrc = w1b + ((size_t)e * F_DIM + 2 * (i0 + il)) * H_DIM + koff;

    ushort_t* ad0a = &As[0][(ww * 32) * 32];
    ushort_t* ad0b = &As[0][(ww * 32 + 16) * 32];
    ushort_t* ad1a = &As[1][(ww * 32) * 32];
    ushort_t* ad1b = &As[1][(ww * 32 + 16) * 32];
    ushort_t* bg0 = &Bg[0][(ww * 16) * 32];
    ushort_t* bg1 = &Bg[1][(ww * 16) * 32];
    ushort_t* bl0 = &Bl[0][(ww * 16) * 32];
    ushort_t* bl1 = &Bl[1][(ww * 16) * 32];

    f32x4 zf = {0.f, 0.f, 0.f, 0.f};
    f32x4 accg[4][2], accl[4][2];
#pragma unroll
    for (int mc = 0; mc < 4; mc++)
#pragma unroll
        for (int nc = 0; nc < 2; nc++) { accg[mc][nc] = zf; accl[mc][nc] = zf; }

    for (int k0 = 0; k0 < H_DIM; k0 += 64) {
        __syncthreads();
        gl_lds16(a0, ad0a);
        gl_lds16(a1, ad0b);
        gl_lds16(a0 + 32, ad1a);
        gl_lds16(a1 + 32, ad1b);
        gl_lds16(bsrc, bg0);
        gl_lds16(bsrc + 32, bg1);
        gl_lds16(bsrc + H_DIM, bl0);
        gl_lds16(bsrc + H_DIM + 32, bl1);
        a0 += 64; a1 += 64; bsrc += 64;
        __syncthreads();

#pragma unroll
        for (int kk = 0; kk < 2; kk++) {
            bf16x8 af[4], bgf[2], blf[2];
#pragma unroll
            for (int mc = 0; mc < 4; mc++)
                af[mc] = *(const bf16x8*)&As[kk][(wm * 64 + mc * 16 + l15) * 32 + quad * 8];
#pragma unroll
            for (int nc = 0; nc < 2; nc++) {
                bgf[nc] = *(const bf16x8*)&Bg[kk][(wn * 32 + nc * 16 + l15) * 32 + quad * 8];
                blf[nc] = *(const bf16x8*)&Bl[kk][(wn * 32 + nc * 16 + l15) * 32 + quad * 8];
            }
#pragma unroll
            for (int mc = 0; mc < 4; mc++)
#pragma unroll
                for (int nc = 0; nc < 2; nc++) {
                    accg[mc][nc] = __builtin_amdgcn_mfma_f32_16x16x32_bf16(
                        af[mc], bgf[nc], accg[mc][nc], 0, 0, 0);
                    accl[mc][nc] = __builtin_amdgcn_mfma_f32_16x16x32_bf16(
                        af[mc], blf[nc], accl[mc][nc], 0, 0, 0);
                }
        }
    }

    // epilogue: bias + swiglu (fast sigmoid), act bf16. D: row=quad*4+r, col=l15.
    int rowbase = off_e + tile * BTM + wm * 64;
    int colbase = i0 + wn * 32;
    float bgc[2], blc[2];
#pragma unroll
    for (int nc = 0; nc < 2; nc++) {
        int i = colbase + nc * 16 + l15;
        bgc[nc] = b1[(size_t)e * F_DIM + 2 * i];
        blc[nc] = b1[(size_t)e * F_DIM + 2 * i + 1];
    }
#pragma unroll
    for (int mc = 0; mc < 4; mc++)
#pragma unroll
        for (int nc = 0; nc < 2; nc++) {
            int i = colbase + nc * 16 + l15;
#pragma unroll
            for (int r = 0; r < 4; r++) {
                int m = rowbase + mc * 16 + quad * 4 + r;
                float g = accg[mc][nc][r] + bgc[nc];
                float l = accl[mc][nc][r] + blc[nc];
                float s = __builtin_amdgcn_rcpf(
                    1.f + __builtin_amdgcn_exp2f(-ALPHA_LOG2E * g));
                act[(size_t)m * I_DIM + i] = f2bf(g * s * (l + 1.f));
            }
        }
}

// fc2: 128 pair-rows x 128 h, BK=64 split sub-tiles. Writes ybuf bf16
// (bias fused); combine gathers per token (no atomics).
__global__ __launch_bounds__(256, 3) void fc2_mfma(
    const ushort_t* __restrict__ act, const ushort_t* __restrict__ w2b,
    const float* __restrict__ b2, const int* __restrict__ cnt,
    ushort_t* __restrict__ ybuf) {
    int e = blockIdx.y >> 5;
    int tile = blockIdx.y & 31;
    int off_e, cpad_e;
    calc_off(cnt, e, off_e, cpad_e);
    if (tile * BTM >= cpad_e) return;
    int h0 = blockIdx.x * 128;
    int rowbase = off_e + tile * BTM;

    __shared__ ushort_t As[2][128 * 32];
    __shared__ ushort_t Bs[2][128 * 32];

    int tid = threadIdx.x;
    int lane = tid & 63;
    int ww = tid >> 6;
    int wm = ww & 1, wn = ww >> 1;
    int l15 = lane & 15, quad = lane >> 4;
    int r4 = lane >> 2;
    int koff = (lane & 3) * 8;

    int ar = ww * 32 + r4;
    const ushort_t* a0 = act + (size_t)(rowbase + ar) * I_DIM + koff;
    const ushort_t* a1 = a0 + (size_t)16 * I_DIM;
    const ushort_t* b0 = w2b + ((size_t)e * H_DIM + h0 + ar) * I_DIM + koff;
    const ushort_t* b1p = b0 + (size_t)16 * I_DIM;

    ushort_t* ad0a = &As[0][(ww * 32) * 32];
    ushort_t* ad0b = &As[0][(ww * 32 + 16) * 32];
    ushort_t* ad1a = &As[1][(ww * 32) * 32];
    ushort_t* ad1b = &As[1][(ww * 32 + 16) * 32];
    ushort_t* bd0a = &Bs[0][(ww * 32) * 32];
    ushort_t* bd0b = &Bs[0][(ww * 32 + 16) * 32];
    ushort_t* bd1a = &Bs[1][(ww * 32) * 32];
    ushort_t* bd1b = &Bs[1][(ww * 32 + 16) * 32];

    f32x4 zf = {0.f, 0.f, 0.f, 0.f};
    f32x4 acc[4][4];
#pragma unroll
    for (int mc = 0; mc < 4; mc++)
#pragma unroll
        for (int nc = 0; nc < 4; nc++) acc[mc][nc] = zf;

    for (int k0 = 0; k0 < I_DIM; k0 += 64) {
        __syncthreads();
        gl_lds16(a0, ad0a);
        gl_lds16(a1, ad0b);
        gl_lds16(a0 + 32, ad1a);
        gl_lds16(a1 + 32, ad1b);
        gl_lds16(b0, bd0a);
        gl_lds16(b1p, bd0b);
        gl_lds16(b0 + 32, bd1a);
        gl_lds16(b1p + 32, bd1b);
        a0 += 64; a1 += 64; b0 += 64; b1p += 64;
        __syncthreads();

#pragma unroll
        for (int kk = 0; kk < 2; kk++) {
            bf16x8 af[4], bf[4];
#pragma unroll
            for (int mc = 0; mc < 4; mc++)
                af[mc] = *(const bf16x8*)&As[kk][(wm * 64 + mc * 16 + l15) * 32 + quad * 8];
#pragma unroll
            for (int nc = 0; nc < 4; nc++)
                bf[nc] = *(const bf16x8*)&Bs[kk][(wn * 64 + nc * 16 + l15) * 32 + quad * 8];
#pragma unroll
            for (int mc = 0; mc < 4; mc++)
#pragma unroll
                for (int nc = 0; nc < 4; nc++)
                    acc[mc][nc] = __builtin_amdgcn_mfma_f32_16x16x32_bf16(
                        af[mc], bf[nc], acc[mc][nc], 0, 0, 0);
        }
    }

    float bc[4];
#pragma unroll
    for (int nc = 0; nc < 4; nc++)
        bc[nc] = b2[(size_t)e * H_DIM + h0 + wn * 64 + nc * 16 + l15];
#pragma unroll
    for (int mc = 0; mc < 4; mc++)
#pragma unroll
        for (int nc = 0; nc < 4; nc++) {
            int h = h0 + wn * 64 + nc * 16 + l15;
#pragma unroll
            for (int r = 0; r < 4; r++) {
                int m = rowbase + wm * 64 + mc * 16 + quad * 4 + r;
                ybuf[(size_t)m * H_DIM + h] = f2bf(acc[mc][nc][r] + bc[nc]);
            }
        }
}

// combine: out[t] = w0*y[row(e0,p0)] + w1*y[row(e1,p1)]
__global__ __launch_bounds__(256) void combine_kernel(
    const ushort_t* __restrict__ ybuf, const int4* __restrict__ tidx,
    const float2* __restrict__ twgt, const int* __restrict__ cnt,
    float* __restrict__ out) {
    int t = blockIdx.x;
    int4 idx = tidx[t];
    float2 w = twgt[t];
    int offv[E_NUM];
    {
        int o = 0;
#pragma unroll
        for (int q = 0; q < E_NUM; q++) {
            offv[q] = o;
            o += (cnt[q] + BTM - 1) & ~(BTM - 1);
        }
    }
    size_t r0 = (size_t)offv[idx.x] + idx.y;
    size_t r1 = (size_t)offv[idx.z] + idx.w;
    int h = threadIdx.x * 8;
    ushort8v a = *(const ushort8v*)(ybuf + r0 * H_DIM + h);
    ushort8v b = *(const ushort8v*)(ybuf + r1 * H_DIM + h);
    float* op = out + (size_t)t * H_DIM + h;
#pragma unroll
    for (int q = 0; q < 8; q++)
        op[q] = w.x * bf2f(a[q]) + w.y * bf2f(b[q]);
}

// ============================ fp32 fallback path ============================
__global__ __launch_bounds__(64) void gate_fb(
    const float* __restrict__ x, const float* __restrict__ gw,
    int* __restrict__ tok, float* __restrict__ wgt,
    int4* __restrict__ tidx, float2* __restrict__ twgt, int* __restrict__ cnt) {
    int t = blockIdx.x;
    int lane = threadIdx.x;
    const float* xr = x + (size_t)t * H_DIM;
    float acc[E_NUM];
#pragma unroll
    for (int e = 0; e < E_NUM; e++) acc[e] = 0.f;
    for (int j = lane; j < H_DIM; j += 64) {
        float xv = xr[j];
#pragma unroll
        for (int e = 0; e < E_NUM; e++) acc[e] += xv * gw[e * H_DIM + j];
    }
#pragma unroll
    for (int e = 0; e < E_NUM; e++) {
#pragma unroll
        for (int s = 32; s > 0; s >>= 1) acc[e] += __shfl_xor(acc[e], s, 64);
    }
    if (lane == 0) {
        int i0 = 0; float b0 = acc[0];
        for (int e = 1; e < E_NUM; e++) if (acc[e] > b0) { b0 = acc[e]; i0 = e; }
        int i1 = -1; float b1 = -3.0e38f;
        for (int e = 0; e < E_NUM; e++) {
            if (e == i0) continue;
            if (acc[e] > b1) { b1 = acc[e]; i1 = e; }
        }
        float e10 = expf(b1 - b0);
        float w0 = 1.f / (1.f + e10);
        float w1 = 1.f - w0;
        int p0 = atomicAdd(&cnt[i0], 1);
        tok[i0 * T_TOK + p0] = t; wgt[i0 * T_TOK + p0] = w0;
        int p1 = atomicAdd(&cnt[i1], 1);
        tok[i1 * T_TOK + p1] = t; wgt[i1 * T_TOK + p1] = w1;
        tidx[t] = make_int4(i0, p0, i1, p1);
        twgt[t] = make_float2(w0, w1);
    }
}

__global__ __launch_bounds__(256) void pad_kernel(
    int* __restrict__ tok, float* __restrict__ wgt,
    const int* __restrict__ cnt, int* __restrict__ cnt_pad,
    int* __restrict__ off, int tile) {
    __shared__ int s_cnt[E_NUM], s_pad[E_NUM];
    if (threadIdx.x == 0) {
        int o = 0;
        for (int e = 0; e < E_NUM; e++) {
            int c = cnt[e];
            int cp = (c + tile - 1) / tile * tile;
            s_cnt[e] = c; s_pad[e] = cp;
            cnt_pad[e] = cp;
            off[e] = o;
            o += cp;
        }
    }
    __syncthreads();
    for (int e = 0; e < E_NUM; e++) {
        for (int p = s_cnt[e] + (int)threadIdx.x; p < s_pad[e]; p += 256) {
            tok[e * T_TOK + p] = 0;
            wgt[e * T_TOK + p] = 0.f;
        }
    }
}

__global__ __launch_bounds__(256) void fc1_kernel(
    const float* __restrict__ x, const float* __restrict__ w1,
    const float* __restrict__ b1, const int* __restrict__ tok,
    const int* __restrict__ cnt_pad, const int* __restrict__ off,
    ushort_t* __restrict__ act) {
    int e = blockIdx.y >> 6;
    int tile = blockIdx.y & 63;
    if (tile * TILE_M >= cnt_pad[e]) return;
    int i0 = blockIdx.x * 64;
    int f0 = i0 * 2;

    __shared__ float xs[KT][TILE_M + 4];
    __shared__ float wsh[KT][128 + 4];

    int tid = threadIdx.x;
    int tx = tid & 15, ty = tid >> 4;
    int rloc = tid >> 3;
    int c4 = (tid & 7) * 4;

    const int* tlist = tok + e * T_TOK + tile * TILE_M;
    int tk0 = tlist[rloc];
    int tk1 = tlist[rloc + 32];
    const float* xp0 = x + (size_t)tk0 * H_DIM + c4;
    const float* xp1 = x + (size_t)tk1 * H_DIM + c4;
    const float* wp = w1 + ((size_t)e * F_DIM + f0 + rloc) * H_DIM + c4;

    float ga[4][4] = {{0.f}}, la[4][4] = {{0.f}};

    for (int k0 = 0; k0 < H_DIM; k0 += KT) {
        __syncthreads();
        {
            float4 v0 = *(const float4*)(xp0 + k0);
            float4 v1 = *(const float4*)(xp1 + k0);
            xs[c4 + 0][rloc] = v0.x; xs[c4 + 1][rloc] = v0.y;
            xs[c4 + 2][rloc] = v0.z; xs[c4 + 3][rloc] = v0.w;
            xs[c4 + 0][rloc + 32] = v1.x; xs[c4 + 1][rloc + 32] = v1.y;
            xs[c4 + 2][rloc + 32] = v1.z; xs[c4 + 3][rloc + 32] = v1.w;
        }
        {
#pragma unroll
            for (int r = 0; r < 4; r++) {
                float4 v = *(const float4*)(wp + (size_t)(32 * r) * H_DIM + k0);
                int fr = rloc + 32 * r;
                wsh[c4 + 0][fr] = v.x; wsh[c4 + 1][fr] = v.y;
                wsh[c4 + 2][fr] = v.z; wsh[c4 + 3][fr] = v.w;
            }
        }
        __syncthreads();
#pragma unroll
        for (int k = 0; k < KT; k++) {
            float4 xv = *(const float4*)&xs[k][ty * 4];
            float4 wa = *(const float4*)&wsh[k][tx * 8];
            float4 wb = *(const float4*)&wsh[k][tx * 8 + 4];
            float xm[4] = {xv.x, xv.y, xv.z, xv.w};
            float gg[4] = {wa.x, wa.z, wb.x, wb.z};
            float ll[4] = {wa.y, wa.w, wb.y, wb.w};
#pragma unroll
            for (int m = 0; m < 4; m++)
#pragma unroll
                for (int n = 0; n < 4; n++) {
                    ga[m][n] += xm[m] * gg[n];
                    la[m][n] += xm[m] * ll[n];
                }
        }
    }

    int rowbase = off[e] + tile * TILE_M;
    float bg[4], bl[4];
#pragma unroll
    for (int n = 0; n < 4; n++) {
        int i = i0 + tx * 4 + n;
        bg[n] = b1[(size_t)e * F_DIM + 2 * i];
        bl[n] = b1[(size_t)e * F_DIM + 2 * i + 1];
    }
#pragma unroll
    for (int m = 0; m < 4; m++) {
        int row = rowbase + ty * 4 + m;
        ushort_t us[4];
#pragma unroll
        for (int n = 0; n < 4; n++) {
            float g = ga[m][n] + bg[n];
            float l = la[m][n] + bl[n];
            float s = 1.f / (1.f + expf(-ALPHA_C * g));
            us[n] = f2bf(g * s * (l + 1.f));
        }
        *(ushort4*)&act[(size_t)row * I_DIM + i0 + tx * 4] =
            make_ushort4(us[0], us[1], us[2], us[3]);
    }
}

__global__ __launch_bounds__(256) void fc2_kernel(
    const ushort_t* __restrict__ act, const float* __restrict__ w2,
    const float* __restrict__ b2, const int* __restrict__ tok,
    const float* __restrict__ wgt, const int* __restrict__ cnt_pad,
    const int* __restrict__ off, float* __restrict__ out) {
    int e = blockIdx.y >> 6;
    int tile = blockIdx.y & 63;
    if (tile * TILE_M >= cnt_pad[e]) return;
    int h0 = blockIdx.x * 64;

    __shared__ float as_[KT][TILE_M + 4];
    __shared__ float wsh[KT][64 + 4];

    int tid = threadIdx.x;
    int tx = tid & 15, ty = tid >> 4;
    int rowbase = off[e] + tile * TILE_M;

    int arow = tid >> 2;
    int ac8 = (tid & 3) * 8;
    const ushort_t* ap = act + (size_t)(rowbase + arow) * I_DIM + ac8;
    int rloc = tid >> 3;
    int c4 = (tid & 7) * 4;
    const float* wp = w2 + ((size_t)e * H_DIM + h0 + rloc) * I_DIM + c4;

    float acc[4][4] = {{0.f}};

    for (int k0 = 0; k0 < I_DIM; k0 += KT) {
        __syncthreads();
        {
            ushort8v v = *(const ushort8v*)(ap + k0);
#pragma unroll
            for (int q = 0; q < 8; q++) as_[ac8 + q][arow] = bf2f(v[q]);
        }
        {
#pragma unroll
            for (int r = 0; r < 2; r++) {
                float4 v = *(const float4*)(wp + (size_t)(32 * r) * I_DIM + k0);
                int hr = rloc + 32 * r;
                wsh[c4 + 0][hr] = v.x; wsh[c4 + 1][hr] = v.y;
                wsh[c4 + 2][hr] = v.z; wsh[c4 + 3][hr] = v.w;
            }
        }
        __syncthreads();
#pragma unroll
        for (int k = 0; k < KT; k++) {
            float4 xv = *(const float4*)&as_[k][ty * 4];
            float4 wv = *(const float4*)&wsh[k][tx * 4];
            float xm[4] = {xv.x, xv.y, xv.z, xv.w};
            float wn[4] = {wv.x, wv.y, wv.z, wv.w};
#pragma unroll
            for (int m = 0; m < 4; m++)
#pragma unroll
                for (int n = 0; n < 4; n++) acc[m][n] += xm[m] * wn[n];
        }
    }

    const int* tlist = tok + e * T_TOK + tile * TILE_M;
    const float* wlist = wgt + e * T_TOK + tile * TILE_M;
#pragma unroll
    for (int m = 0; m < 4; m++) {
        int row = ty * 4 + m;
        int t = tlist[row];
        float w = wlist[row];
        if (w == 0.f) continue;
#pragma unroll
        for (int n = 0; n < 4; n++) {
            int h = h0 + tx * 4 + n;
            float y = acc[m][n] + b2[(size_t)e * H_DIM + h];
            atomicAdd(out + (size_t)t * H_DIM + h, w * y);
        }
    }
}

// --------------------------------------------------------------- launch -----
extern "C" void kernel_launch(void* const* d_in, const int* in_sizes, int n_in,
                              void* d_out, int out_size, void* d_ws, size_t ws_size,
                              hipStream_t stream) {
    const float* x  = (const float*)d_in[0];
    const float* gw = (const float*)d_in[1];
    const float* w1 = (const float*)d_in[2];
    const float* b1 = (const float*)d_in[3];
    const float* w2 = (const float*)d_in[4];
    const float* b2 = (const float*)d_in[5];
    float* out = (float*)d_out;
    char* ws = (char*)d_ws;

    size_t w1b_sz = (size_t)E_NUM * F_DIM * H_DIM * 2;  // 134217728
    size_t w2b_sz = (size_t)E_NUM * H_DIM * I_DIM * 2;  // 67108864
    size_t xb_sz  = (size_t)T_TOK * H_DIM * 2;          // 16777216
    size_t act_sz = (size_t)ACT_CAP_B * I_DIM * 2;      // 37748736
    size_t tok_sz = (size_t)E_NUM * T_TOK * 4;          // 131072
    size_t tidx_sz = (size_t)T_TOK * 16;
    size_t twgt_sz = (size_t)T_TOK * 8;
    size_t need_big = w1b_sz + w2b_sz + xb_sz + act_sz + tok_sz + 64 +
                      tidx_sz + twgt_sz + 256;

    if (ws_size >= need_big) {
        ushort_t* w1b = (ushort_t*)ws;                       // also ybuf later
        ushort_t* w2b = (ushort_t*)(ws + w1b_sz);
        ushort_t* xb  = (ushort_t*)(ws + w1b_sz + w2b_sz);
        ushort_t* act = (ushort_t*)(ws + w1b_sz + w2b_sz + xb_sz);
        char* p = ws + w1b_sz + w2b_sz + xb_sz + act_sz;
        int*    tok  = (int*)p;                 p += tok_sz;
        int*    cnt  = (int*)p;                 p += 64;   // adjacent to tok
        int4*   tidx = (int4*)p;                p += tidx_sz;
        float2* twgt = (float2*)p;
        ushort_t* ybuf = w1b;   // w1b dead after fc1

        // zero tok lists + cnt in one shot: padding = token 0 for free
        hipMemsetAsync(tok, 0, tok_sz + 64, stream);
        prep_kernel<<<GATE_BLOCKS + CVT_BLOCKS, 256, 0, stream>>>(
            x, gw, w1, w1b, xb, tok, tidx, twgt, cnt);
        fc1_mfma<<<dim3(I_DIM / 64 + W2X, E_NUM * 32), 256, 0, stream>>>(
            xb, w1b, b1, tok, cnt, act, w2, w2b);
        fc2_mfma<<<dim3(H_DIM / 128, E_NUM * 32), 256, 0, stream>>>(
            act, w2b, b2, cnt, ybuf);
        combine_kernel<<<T_TOK, 256, 0, stream>>>(ybuf, tidx, twgt, cnt, out);
        return;
    }

    // fp32 fallback (round-1 proven)
    size_t actB = (size_t)ACT_CAP_F * I_DIM * 2;
    ushort_t* act = (ushort_t*)ws;
    char* p = ws + actB;
    int*    tok  = (int*)p;     p += tok_sz;
    float*  wgt  = (float*)p;   p += tok_sz;
    int4*   tidx = (int4*)p;    p += tidx_sz;
    float2* twgt = (float2*)p;  p += twgt_sz;
    int*    cnt  = (int*)p;
    int*    cnt_pad = cnt + E_NUM;
    int*    off  = cnt_pad + E_NUM;
    size_t need = actB + 2 * tok_sz + tidx_sz + twgt_sz + 256;
    if (ws_size < need) return;

    hipMemsetAsync(cnt, 0, E_NUM * sizeof(int), stream);
    hipMemsetAsync(d_out, 0, (size_t)T_TOK * H_DIM * sizeof(float), stream);
    gate_fb<<<T_TOK, 64, 0, stream>>>(x, gw, tok, wgt, tidx, twgt, cnt);
    pad_kernel<<<1, 256, 0, stream>>>(tok, wgt, cnt, cnt_pad, off, TILE_M);
    fc1_kernel<<<dim3(I_DIM / 64, E_NUM * 64), 256, 0, stream>>>(
        x, w1, b1, tok, cnt_pad, off, act);
    fc2_kernel<<<dim3(H_DIM / 64, E_NUM * 64), 256, 0, stream>>>(
        act, w2, b2, tok, wgt, cnt_pad, off, out);
}

// Round 2
// 846.154 us; speedup vs baseline: 1.1151x; 1.1151x over previous
//
#include <hip/hip_runtime.h>
#include <math.h>

// SwigluMoE routed, round 6: 5-dispatch pipeline (round-0 structure restored).
//   memset(tok,cnt) -> prep(gate + x->bf16 + w1/w2->bf16) -> fc1 -> fc2 -> combine
// R6 changes vs R5 (both R5 ideas regressed; see journal):
//   * REVERTED nontemporal loads (they killed cross-iteration L3 residency of
//     the f32 weights: FETCH + ~200MB/pass)
//   * REVERTED w2-cvt riders in fc1 (they competed with fc1's own ~340MB
//     fetch stream: fc1 268us, MfmaUtil 22%)
//   * prep cvt is now EXACT-TRIP: one 32-float chunk per thread, 8 cached
//     float4 loads issued back-to-back (128B/lane in flight, no runtime loop)
//     -> tests the latency/MLP theory for prep's 1.9TB/s cleanly.
// fc1/fc2: m97-style global_load_lds BK=64 bf16 MFMA (unchanged).
// T=4096, H=2048, I=2048 (2I=4096), E=8, top-2. Routed = 206 GFLOP.

#define T_TOK 4096
#define H_DIM 2048
#define I_DIM 2048
#define F_DIM 4096   // 2*I
#define E_NUM 8
#define ALPHA_C 1.702f
#define ALPHA_LOG2E 2.4554674f   // 1.702 * log2(e)

// fp32 fallback tiling
#define TILE_M 64
#define KT 32
#define ACT_CAP_F (2 * T_TOK + E_NUM * TILE_M)   // 8704
// bf16 path tiling
#define BTM 128
#define ACT_CAP_B (2 * T_TOK + E_NUM * BTM)      // 9216

#define GATE_BLOCKS (T_TOK / 4)   // 1024
#define N1Q 2097152               // w1 floats / 32  (8*4096*2048/32)
#define N2Q 1048576               // w2 floats / 32  (8*2048*2048/32)
#define CVT_BLOCKS ((N1Q + N2Q) / 256)   // 12288, exact one chunk per thread

typedef unsigned short ushort_t;
typedef __attribute__((ext_vector_type(8))) unsigned short ushort8v;
typedef __attribute__((ext_vector_type(8))) __bf16 bf16x8;
typedef __attribute__((ext_vector_type(4))) float f32x4;

__device__ __forceinline__ ushort_t f2bf(float f) {
    unsigned int u = __float_as_uint(f);
    unsigned int r = (u + 0x7FFFu + ((u >> 16) & 1u)) >> 16;  // RNE
    return (ushort_t)r;
}
__device__ __forceinline__ float bf2f(ushort_t b) {
    return __uint_as_float(((unsigned int)b) << 16);
}

__device__ __forceinline__ void gl_lds16(const ushort_t* g, ushort_t* l) {
    __builtin_amdgcn_global_load_lds(
        (const __attribute__((address_space(1))) void*)g,
        (__attribute__((address_space(3))) void*)l, 16, 0, 0);
}

// convert 32 consecutive floats -> 32 bf16. 8 cached float4 loads issued
// back-to-back (128 B/lane in flight), 4x ushort8 stores (bf16 copy is
// re-read by fc1/fc2 -> keep cacheable both sides; L3 holds f32 weights
// across bench iterations, worth ~200MB/pass of FETCH).
__device__ __forceinline__ void cvt32(const float* __restrict__ s,
                                      ushort_t* __restrict__ d) {
    f32x4 v[8];
#pragma unroll
    for (int j = 0; j < 8; j++)
        v[j] = *(const f32x4*)(s + 4 * j);
#pragma unroll
    for (int g = 0; g < 4; g++) {
        ushort8v o;
#pragma unroll
        for (int k = 0; k < 8; k++)
            o[k] = f2bf(v[2 * g + (k >> 2)][k & 3]);
        *(ushort8v*)(d + 8 * g) = o;
    }
}

// ---------------------------------------------------------------- prep ------
// blocks [0, GATE_BLOCKS): gating (4 tokens/block, 1 wave each) + x->bf16.
// blocks [GATE_BLOCKS, +CVT_BLOCKS): w1||w2 -> bf16, exactly 32 floats/thread.
__global__ __launch_bounds__(256) void prep_kernel(
    const float* __restrict__ x, const float* __restrict__ gw,
    const float* __restrict__ w1, const float* __restrict__ w2,
    ushort_t* __restrict__ wb, ushort_t* __restrict__ xb,
    int* __restrict__ tok, int4* __restrict__ tidx, float2* __restrict__ twgt,
    int* __restrict__ cnt) {
    if (blockIdx.x < GATE_BLOCKS) {
        int t = blockIdx.x * 4 + (threadIdx.x >> 6);
        int lane = threadIdx.x & 63;
        const float* xr = x + (size_t)t * H_DIM;
        ushort_t* xbr = xb + (size_t)t * H_DIM;
        float acc[E_NUM];
#pragma unroll
        for (int e = 0; e < E_NUM; e++) acc[e] = 0.f;
#pragma unroll
        for (int i = 0; i < H_DIM / 256; i++) {
            int j = (i * 64 + lane) * 4;
            float4 xv = *(const float4*)(xr + j);
            *(ushort4*)(xbr + j) =
                make_ushort4(f2bf(xv.x), f2bf(xv.y), f2bf(xv.z), f2bf(xv.w));
#pragma unroll
            for (int e = 0; e < E_NUM; e++) {
                float4 g = *(const float4*)(gw + e * H_DIM + j);
                acc[e] += xv.x * g.x + xv.y * g.y + xv.z * g.z + xv.w * g.w;
            }
        }
#pragma unroll
        for (int e = 0; e < E_NUM; e++) {
#pragma unroll
            for (int s = 32; s > 0; s >>= 1) acc[e] += __shfl_xor(acc[e], s, 64);
        }
        if (lane == 0) {
            int i0 = 0; float b0 = acc[0];
            for (int e = 1; e < E_NUM; e++) if (acc[e] > b0) { b0 = acc[e]; i0 = e; }
            int i1 = -1; float b1 = -3.0e38f;
            for (int e = 0; e < E_NUM; e++) {
                if (e == i0) continue;
                if (acc[e] > b1) { b1 = acc[e]; i1 = e; }
            }
            float e10 = expf(b1 - b0);
            float w0 = 1.f / (1.f + e10);
            float w1v = 1.f - w0;
            int p0 = atomicAdd(&cnt[i0], 1);
            tok[i0 * T_TOK + p0] = t;
            int p1 = atomicAdd(&cnt[i1], 1);
            tok[i1 * T_TOK + p1] = t;
            tidx[t] = make_int4(i0, p0, i1, p1);
            twgt[t] = make_float2(w0, w1v);
        }
    } else {
        int q = (int)(blockIdx.x - GATE_BLOCKS) * 256 + (int)threadIdx.x;
        const float* s = (q < N1Q) ? (w1 + (size_t)q * 32)
                                   : (w2 + ((size_t)(q - N1Q)) * 32);
        cvt32(s, wb + (size_t)q * 32);
    }
}

// helper: padded count prefix from cnt[] (8 L2-hot loads, wave-uniform)
__device__ __forceinline__ void calc_off(const int* __restrict__ cnt, int e,
                                         int& off_e, int& cpad_e) {
    int o = 0, cp = 0;
#pragma unroll
    for (int q = 0; q < E_NUM; q++) {
        int c = (cnt[q] + BTM - 1) & ~(BTM - 1);
        if (q < e) o += c;
        if (q == e) cp = c;
    }
    off_e = o; cpad_e = cp;
}

// ============================ bf16 MFMA path ================================
// fc1: 128 pair-rows x 64 i (=128 f rows, g/l split tiles). BK=64 as two
// 32-wide sub-tiles (64B row stride: 2-way LDS aliasing free; keeps
// global_load_lds contiguous-lane layout). 4 waves, 2x2.
__global__ __launch_bounds__(256, 3) void fc1_mfma(
    const ushort_t* __restrict__ xb, const ushort_t* __restrict__ w1b,
    const float* __restrict__ b1, const int* __restrict__ tok,
    const int* __restrict__ cnt, ushort_t* __restrict__ act) {
    int e = blockIdx.y >> 5;
    int tile = blockIdx.y & 31;
    int off_e, cpad_e;
    calc_off(cnt, e, off_e, cpad_e);
    if (tile * BTM >= cpad_e) return;
    int i0 = blockIdx.x * 64;

    __shared__ ushort_t As[2][128 * 32];
    __shared__ ushort_t Bg[2][64 * 32];
    __shared__ ushort_t Bl[2][64 * 32];

    int tid = threadIdx.x;
    int lane = tid & 63;
    int ww = tid >> 6;
    int wm = ww & 1, wn = ww >> 1;
    int l15 = lane & 15, quad = lane >> 4;
    int r4 = lane >> 2;           // 0..15
    int koff = (lane & 3) * 8;    // 0,8,16,24

    const int* tlist = tok + e * T_TOK + tile * BTM;
    int ar0 = ww * 32 + r4;
    const ushort_t* a0 = xb + (size_t)tlist[ar0] * H_DIM + koff;
    const ushort_t* a1 = xb + (size_t)tlist[ar0 + 16] * H_DIM + koff;
    int il = ww * 16 + r4;
    const ushort_t* bsrc = w1b + ((size_t)e * F_DIM + 2 * (i0 + il)) * H_DIM + koff;

    ushort_t* ad0a = &As[0][(ww * 32) * 32];
    ushort_t* ad0b = &As[0][(ww * 32 + 16) * 32];
    ushort_t* ad1a = &As[1][(ww * 32) * 32];
    ushort_t* ad1b = &As[1][(ww * 32 + 16) * 32];
    ushort_t* bg0 = &Bg[0][(ww * 16) * 32];
    ushort_t* bg1 = &Bg[1][(ww * 16) * 32];
    ushort_t* bl0 = &Bl[0][(ww * 16) * 32];
    ushort_t* bl1 = &Bl[1][(ww * 16) * 32];

    f32x4 zf = {0.f, 0.f, 0.f, 0.f};
    f32x4 accg[4][2], accl[4][2];
#pragma unroll
    for (int mc = 0; mc < 4; mc++)
#pragma unroll
        for (int nc = 0; nc < 2; nc++) { accg[mc][nc] = zf; accl[mc][nc] = zf; }

    for (int k0 = 0; k0 < H_DIM; k0 += 64) {
        __syncthreads();
        gl_lds16(a0, ad0a);
        gl_lds16(a1, ad0b);
        gl_lds16(a0 + 32, ad1a);
        gl_lds16(a1 + 32, ad1b);
        gl_lds16(bsrc, bg0);
        gl_lds16(bsrc + 32, bg1);
        gl_lds16(bsrc + H_DIM, bl0);
        gl_lds16(bsrc + H_DIM + 32, bl1);
        a0 += 64; a1 += 64; bsrc += 64;
        __syncthreads();

#pragma unroll
        for (int kk = 0; kk < 2; kk++) {
            bf16x8 af[4], bgf[2], blf[2];
#pragma unroll
            for (int mc = 0; mc < 4; mc++)
                af[mc] = *(const bf16x8*)&As[kk][(wm * 64 + mc * 16 + l15) * 32 + quad * 8];
#pragma unroll
            for (int nc = 0; nc < 2; nc++) {
                bgf[nc] = *(const bf16x8*)&Bg[kk][(wn * 32 + nc * 16 + l15) * 32 + quad * 8];
                blf[nc] = *(const bf16x8*)&Bl[kk][(wn * 32 + nc * 16 + l15) * 32 + quad * 8];
            }
#pragma unroll
            for (int mc = 0; mc < 4; mc++)
#pragma unroll
                for (int nc = 0; nc < 2; nc++) {
                    accg[mc][nc] = __builtin_amdgcn_mfma_f32_16x16x32_bf16(
                        af[mc], bgf[nc], accg[mc][nc], 0, 0, 0);
                    accl[mc][nc] = __builtin_amdgcn_mfma_f32_16x16x32_bf16(
                        af[mc], blf[nc], accl[mc][nc], 0, 0, 0);
                }
        }
    }

    // epilogue: bias + swiglu (fast sigmoid), act bf16. D: row=quad*4+r, col=l15.
    int rowbase = off_e + tile * BTM + wm * 64;
    int colbase = i0 + wn * 32;
    float bgc[2], blc[2];
#pragma unroll
    for (int nc = 0; nc < 2; nc++) {
        int i = colbase + nc * 16 + l15;
        bgc[nc] = b1[(size_t)e * F_DIM + 2 * i];
        blc[nc] = b1[(size_t)e * F_DIM + 2 * i + 1];
    }
#pragma unroll
    for (int mc = 0; mc < 4; mc++)
#pragma unroll
        for (int nc = 0; nc < 2; nc++) {
            int i = colbase + nc * 16 + l15;
#pragma unroll
            for (int r = 0; r < 4; r++) {
                int m = rowbase + mc * 16 + quad * 4 + r;
                float g = accg[mc][nc][r] + bgc[nc];
                float l = accl[mc][nc][r] + blc[nc];
                float s = __builtin_amdgcn_rcpf(
                    1.f + __builtin_amdgcn_exp2f(-ALPHA_LOG2E * g));
                act[(size_t)m * I_DIM + i] = f2bf(g * s * (l + 1.f));
            }
        }
}

// fc2: 128 pair-rows x 128 h, BK=64 split sub-tiles. Writes ybuf bf16
// (bias fused); combine gathers per token (no atomics).
__global__ __launch_bounds__(256, 3) void fc2_mfma(
    const ushort_t* __restrict__ act, const ushort_t* __restrict__ w2b,
    const float* __restrict__ b2, const int* __restrict__ cnt,
    ushort_t* __restrict__ ybuf) {
    int e = blockIdx.y >> 5;
    int tile = blockIdx.y & 31;
    int off_e, cpad_e;
    calc_off(cnt, e, off_e, cpad_e);
    if (tile * BTM >= cpad_e) return;
    int h0 = blockIdx.x * 128;
    int rowbase = off_e + tile * BTM;

    __shared__ ushort_t As[2][128 * 32];
    __shared__ ushort_t Bs[2][128 * 32];

    int tid = threadIdx.x;
    int lane = tid & 63;
    int ww = tid >> 6;
    int wm = ww & 1, wn = ww >> 1;
    int l15 = lane & 15, quad = lane >> 4;
    int r4 = lane >> 2;
    int koff = (lane & 3) * 8;

    int ar = ww * 32 + r4;
    const ushort_t* a0 = act + (size_t)(rowbase + ar) * I_DIM + koff;
    const ushort_t* a1 = a0 + (size_t)16 * I_DIM;
    const ushort_t* b0 = w2b + ((size_t)e * H_DIM + h0 + ar) * I_DIM + koff;
    const ushort_t* b1p = b0 + (size_t)16 * I_DIM;

    ushort_t* ad0a = &As[0][(ww * 32) * 32];
    ushort_t* ad0b = &As[0][(ww * 32 + 16) * 32];
    ushort_t* ad1a = &As[1][(ww * 32) * 32];
    ushort_t* ad1b = &As[1][(ww * 32 + 16) * 32];
    ushort_t* bd0a = &Bs[0][(ww * 32) * 32];
    ushort_t* bd0b = &Bs[0][(ww * 32 + 16) * 32];
    ushort_t* bd1a = &Bs[1][(ww * 32) * 32];
    ushort_t* bd1b = &Bs[1][(ww * 32 + 16) * 32];

    f32x4 zf = {0.f, 0.f, 0.f, 0.f};
    f32x4 acc[4][4];
#pragma unroll
    for (int mc = 0; mc < 4; mc++)
#pragma unroll
        for (int nc = 0; nc < 4; nc++) acc[mc][nc] = zf;

    for (int k0 = 0; k0 < I_DIM; k0 += 64) {
        __syncthreads();
        gl_lds16(a0, ad0a);
        gl_lds16(a1, ad0b);
        gl_lds16(a0 + 32, ad1a);
        gl_lds16(a1 + 32, ad1b);
        gl_lds16(b0, bd0a);
        gl_lds16(b1p, bd0b);
        gl_lds16(b0 + 32, bd1a);
        gl_lds16(b1p + 32, bd1b);
        a0 += 64; a1 += 64; b0 += 64; b1p += 64;
        __syncthreads();

#pragma unroll
        for (int kk = 0; kk < 2; kk++) {
            bf16x8 af[4], bf[4];
#pragma unroll
            for (int mc = 0; mc < 4; mc++)
                af[mc] = *(const bf16x8*)&As[kk][(wm * 64 + mc * 16 + l15) * 32 + quad * 8];
#pragma unroll
            for (int nc = 0; nc < 4; nc++)
                bf[nc] = *(const bf16x8*)&Bs[kk][(wn * 64 + nc * 16 + l15) * 32 + quad * 8];
#pragma unroll
            for (int mc = 0; mc < 4; mc++)
#pragma unroll
                for (int nc = 0; nc < 4; nc++)
                    acc[mc][nc] = __builtin_amdgcn_mfma_f32_16x16x32_bf16(
                        af[mc], bf[nc], acc[mc][nc], 0, 0, 0);
        }
    }

    float bc[4];
#pragma unroll
    for (int nc = 0; nc < 4; nc++)
        bc[nc] = b2[(size_t)e * H_DIM + h0 + wn * 64 + nc * 16 + l15];
#pragma unroll
    for (int mc = 0; mc < 4; mc++)
#pragma unroll
        for (int nc = 0; nc < 4; nc++) {
            int h = h0 + wn * 64 + nc * 16 + l15;
#pragma unroll
            for (int r = 0; r < 4; r++) {
                int m = rowbase + wm * 64 + mc * 16 + quad * 4 + r;
                ybuf[(size_t)m * H_DIM + h] = f2bf(acc[mc][nc][r] + bc[nc]);
            }
        }
}

// combine: out[t] = w0*y[row(e0,p0)] + w1*y[row(e1,p1)]
__global__ __launch_bounds__(256) void combine_kernel(
    const ushort_t* __restrict__ ybuf, const int4* __restrict__ tidx,
    const float2* __restrict__ twgt, const int* __restrict__ cnt,
    float* __restrict__ out) {
    int t = blockIdx.x;
    int4 idx = tidx[t];
    float2 w = twgt[t];
    int offv[E_NUM];
    {
        int o = 0;
#pragma unroll
        for (int q = 0; q < E_NUM; q++) {
            offv[q] = o;
            o += (cnt[q] + BTM - 1) & ~(BTM - 1);
        }
    }
    size_t r0 = (size_t)offv[idx.x] + idx.y;
    size_t r1 = (size_t)offv[idx.z] + idx.w;
    int h = threadIdx.x * 8;
    ushort8v a = *(const ushort8v*)(ybuf + r0 * H_DIM + h);
    ushort8v b = *(const ushort8v*)(ybuf + r1 * H_DIM + h);
    float* op = out + (size_t)t * H_DIM + h;
#pragma unroll
    for (int q = 0; q < 8; q++)
        op[q] = w.x * bf2f(a[q]) + w.y * bf2f(b[q]);
}

// ============================ fp32 fallback path ============================
__global__ __launch_bounds__(64) void gate_fb(
    const float* __restrict__ x, const float* __restrict__ gw,
    int* __restrict__ tok, float* __restrict__ wgt,
    int4* __restrict__ tidx, float2* __restrict__ twgt, int* __restrict__ cnt) {
    int t = blockIdx.x;
    int lane = threadIdx.x;
    const float* xr = x + (size_t)t * H_DIM;
    float acc[E_NUM];
#pragma unroll
    for (int e = 0; e < E_NUM; e++) acc[e] = 0.f;
    for (int j = lane; j < H_DIM; j += 64) {
        float xv = xr[j];
#pragma unroll
        for (int e = 0; e < E_NUM; e++) acc[e] += xv * gw[e * H_DIM + j];
    }
#pragma unroll
    for (int e = 0; e < E_NUM; e++) {
#pragma unroll
        for (int s = 32; s > 0; s >>= 1) acc[e] += __shfl_xor(acc[e], s, 64);
    }
    if (lane == 0) {
        int i0 = 0; float b0 = acc[0];
        for (int e = 1; e < E_NUM; e++) if (acc[e] > b0) { b0 = acc[e]; i0 = e; }
        int i1 = -1; float b1 = -3.0e38f;
        for (int e = 0; e < E_NUM; e++) {
            if (e == i0) continue;
            if (acc[e] > b1) { b1 = acc[e]; i1 = e; }
        }
        float e10 = expf(b1 - b0);
        float w0 = 1.f / (1.f + e10);
        float w1 = 1.f - w0;
        int p0 = atomicAdd(&cnt[i0], 1);
        tok[i0 * T_TOK + p0] = t; wgt[i0 * T_TOK + p0] = w0;
        int p1 = atomicAdd(&cnt[i1], 1);
        tok[i1 * T_TOK + p1] = t; wgt[i1 * T_TOK + p1] = w1;
        tidx[t] = make_int4(i0, p0, i1, p1);
        twgt[t] = make_float2(w0, w1);
    }
}

__global__ __launch_bounds__(256) void pad_kernel(
    int* __restrict__ tok, float* __restrict__ wgt,
    const int* __restrict__ cnt, int* __restrict__ cnt_pad,
    int* __restrict__ off, int tile) {
    __shared__ int s_cnt[E_NUM], s_pad[E_NUM];
    if (threadIdx.x == 0) {
        int o = 0;
        for (int e = 0; e < E_NUM; e++) {
            int c = cnt[e];
            int cp = (c + tile - 1) / tile * tile;
            s_cnt[e] = c; s_pad[e] = cp;
            cnt_pad[e] = cp;
            off[e] = o;
            o += cp;
        }
    }
    __syncthreads();
    for (int e = 0; e < E_NUM; e++) {
        for (int p = s_cnt[e] + (int)threadIdx.x; p < s_pad[e]; p += 256) {
            tok[e * T_TOK + p] = 0;
            wgt[e * T_TOK + p] = 0.f;
        }
    }
}

__global__ __launch_bounds__(256) void fc1_kernel(
    const float* __restrict__ x, const float* __restrict__ w1,
    const float* __restrict__ b1, const int* __restrict__ tok,
    const int* __restrict__ cnt_pad, const int* __restrict__ off,
    ushort_t* __restrict__ act) {
    int e = blockIdx.y >> 6;
    int tile = blockIdx.y & 63;
    if (tile * TILE_M >= cnt_pad[e]) return;
    int i0 = blockIdx.x * 64;
    int f0 = i0 * 2;

    __shared__ float xs[KT][TILE_M + 4];
    __shared__ float wsh[KT][128 + 4];

    int tid = threadIdx.x;
    int tx = tid & 15, ty = tid >> 4;
    int rloc = tid >> 3;
    int c4 = (tid & 7) * 4;

    const int* tlist = tok + e * T_TOK + tile * TILE_M;
    int tk0 = tlist[rloc];
    int tk1 = tlist[rloc + 32];
    const float* xp0 = x + (size_t)tk0 * H_DIM + c4;
    const float* xp1 = x + (size_t)tk1 * H_DIM + c4;
    const float* wp = w1 + ((size_t)e * F_DIM + f0 + rloc) * H_DIM + c4;

    float ga[4][4] = {{0.f}}, la[4][4] = {{0.f}};

    for (int k0 = 0; k0 < H_DIM; k0 += KT) {
        __syncthreads();
        {
            float4 v0 = *(const float4*)(xp0 + k0);
            float4 v1 = *(const float4*)(xp1 + k0);
            xs[c4 + 0][rloc] = v0.x; xs[c4 + 1][rloc] = v0.y;
            xs[c4 + 2][rloc] = v0.z; xs[c4 + 3][rloc] = v0.w;
            xs[c4 + 0][rloc + 32] = v1.x; xs[c4 + 1][rloc + 32] = v1.y;
            xs[c4 + 2][rloc + 32] = v1.z; xs[c4 + 3][rloc + 32] = v1.w;
        }
        {
#pragma unroll
            for (int r = 0; r < 4; r++) {
                float4 v = *(const float4*)(wp + (size_t)(32 * r) * H_DIM + k0);
                int fr = rloc + 32 * r;
                wsh[c4 + 0][fr] = v.x; wsh[c4 + 1][fr] = v.y;
                wsh[c4 + 2][fr] = v.z; wsh[c4 + 3][fr] = v.w;
            }
        }
        __syncthreads();
#pragma unroll
        for (int k = 0; k < KT; k++) {
            float4 xv = *(const float4*)&xs[k][ty * 4];
            float4 wa = *(const float4*)&wsh[k][tx * 8];
            float4 wb = *(const float4*)&wsh[k][tx * 8 + 4];
            float xm[4] = {xv.x, xv.y, xv.z, xv.w};
            float gg[4] = {wa.x, wa.z, wb.x, wb.z};
            float ll[4] = {wa.y, wa.w, wb.y, wb.w};
#pragma unroll
            for (int m = 0; m < 4; m++)
#pragma unroll
                for (int n = 0; n < 4; n++) {
                    ga[m][n] += xm[m] * gg[n];
                    la[m][n] += xm[m] * ll[n];
                }
        }
    }

    int rowbase = off[e] + tile * TILE_M;
    float bg[4], bl[4];
#pragma unroll
    for (int n = 0; n < 4; n++) {
        int i = i0 + tx * 4 + n;
        bg[n] = b1[(size_t)e * F_DIM + 2 * i];
        bl[n] = b1[(size_t)e * F_DIM + 2 * i + 1];
    }
#pragma unroll
    for (int m = 0; m < 4; m++) {
        int row = rowbase + ty * 4 + m;
        ushort_t us[4];
#pragma unroll
        for (int n = 0; n < 4; n++) {
            float g = ga[m][n] + bg[n];
            float l = la[m][n] + bl[n];
            float s = 1.f / (1.f + expf(-ALPHA_C * g));
            us[n] = f2bf(g * s * (l + 1.f));
        }
        *(ushort4*)&act[(size_t)row * I_DIM + i0 + tx * 4] =
            make_ushort4(us[0], us[1], us[2], us[3]);
    }
}

__global__ __launch_bounds__(256) void fc2_kernel(
    const ushort_t* __restrict__ act, const float* __restrict__ w2,
    const float* __restrict__ b2, const int* __restrict__ tok,
    const float* __restrict__ wgt, const int* __restrict__ cnt_pad,
    const int* __restrict__ off, float* __restrict__ out) {
    int e = blockIdx.y >> 6;
    int tile = blockIdx.y & 63;
    if (tile * TILE_M >= cnt_pad[e]) return;
    int h0 = blockIdx.x * 64;

    __shared__ float as_[KT][TILE_M + 4];
    __shared__ float wsh[KT][64 + 4];

    int tid = threadIdx.x;
    int tx = tid & 15, ty = tid >> 4;
    int rowbase = off[e] + tile * TILE_M;

    int arow = tid >> 2;
    int ac8 = (tid & 3) * 8;
    const ushort_t* ap = act + (size_t)(rowbase + arow) * I_DIM + ac8;
    int rloc = tid >> 3;
    int c4 = (tid & 7) * 4;
    const float* wp = w2 + ((size_t)e * H_DIM + h0 + rloc) * I_DIM + c4;

    float acc[4][4] = {{0.f}};

    for (int k0 = 0; k0 < I_DIM; k0 += KT) {
        __syncthreads();
        {
            ushort8v v = *(const ushort8v*)(ap + k0);
#pragma unroll
            for (int q = 0; q < 8; q++) as_[ac8 + q][arow] = bf2f(v[q]);
        }
        {
#pragma unroll
            for (int r = 0; r < 2; r++) {
                float4 v = *(const float4*)(wp + (size_t)(32 * r) * I_DIM + k0);
                int hr = rloc + 32 * r;
                wsh[c4 + 0][hr] = v.x; wsh[c4 + 1][hr] = v.y;
                wsh[c4 + 2][hr] = v.z; wsh[c4 + 3][hr] = v.w;
            }
        }
        __syncthreads();
#pragma unroll
        for (int k = 0; k < KT; k++) {
            float4 xv = *(const float4*)&as_[k][ty * 4];
            float4 wv = *(const float4*)&wsh[k][tx * 4];
            float xm[4] = {xv.x, xv.y, xv.z, xv.w};
            float wn[4] = {wv.x, wv.y, wv.z, wv.w};
#pragma unroll
            for (int m = 0; m < 4; m++)
#pragma unroll
                for (int n = 0; n < 4; n++) acc[m][n] += xm[m] * wn[n];
        }
    }

    const int* tlist = tok + e * T_TOK + tile * TILE_M;
    const float* wlist = wgt + e * T_TOK + tile * TILE_M;
#pragma unroll
    for (int m = 0; m < 4; m++) {
        int row = ty * 4 + m;
        int t = tlist[row];
        float w = wlist[row];
        if (w == 0.f) continue;
#pragma unroll
        for (int n = 0; n < 4; n++) {
            int h = h0 + tx * 4 + n;
            float y = acc[m][n] + b2[(size_t)e * H_DIM + h];
            atomicAdd(out + (size_t)t * H_DIM + h, w * y);
        }
    }
}

// --------------------------------------------------------------- launch -----
extern "C" void kernel_launch(void* const* d_in, const int* in_sizes, int n_in,
                              void* d_out, int out_size, void* d_ws, size_t ws_size,
                              hipStream_t stream) {
    const float* x  = (const float*)d_in[0];
    const float* gw = (const float*)d_in[1];
    const float* w1 = (const float*)d_in[2];
    const float* b1 = (const float*)d_in[3];
    const float* w2 = (const float*)d_in[4];
    const float* b2 = (const float*)d_in[5];
    float* out = (float*)d_out;
    char* ws = (char*)d_ws;

    size_t w1b_sz = (size_t)E_NUM * F_DIM * H_DIM * 2;  // 134217728
    size_t w2b_sz = (size_t)E_NUM * H_DIM * I_DIM * 2;  // 67108864
    size_t xb_sz  = (size_t)T_TOK * H_DIM * 2;          // 16777216
    size_t act_sz = (size_t)ACT_CAP_B * I_DIM * 2;      // 37748736
    size_t tok_sz = (size_t)E_NUM * T_TOK * 4;          // 131072
    size_t tidx_sz = (size_t)T_TOK * 16;
    size_t twgt_sz = (size_t)T_TOK * 8;
    size_t need_big = w1b_sz + w2b_sz + xb_sz + act_sz + tok_sz + 64 +
                      tidx_sz + twgt_sz + 256;

    if (ws_size >= need_big) {
        ushort_t* w1b = (ushort_t*)ws;                       // also ybuf later
        ushort_t* w2b = (ushort_t*)(ws + w1b_sz);
        ushort_t* xb  = (ushort_t*)(ws + w1b_sz + w2b_sz);
        ushort_t* act = (ushort_t*)(ws + w1b_sz + w2b_sz + xb_sz);
        char* p = ws + w1b_sz + w2b_sz + xb_sz + act_sz;
        int*    tok  = (int*)p;                 p += tok_sz;
        int*    cnt  = (int*)p;                 p += 64;   // adjacent to tok
        int4*   tidx = (int4*)p;                p += tidx_sz;
        float2* twgt = (float2*)p;
        ushort_t* ybuf = w1b;   // w1b dead after fc1

        // zero tok lists + cnt in one shot: padding = token 0 for free
        hipMemsetAsync(tok, 0, tok_sz + 64, stream);
        prep_kernel<<<GATE_BLOCKS + CVT_BLOCKS, 256, 0, stream>>>(
            x, gw, w1, w2, w1b, xb, tok, tidx, twgt, cnt);
        fc1_mfma<<<dim3(I_DIM / 64, E_NUM * 32), 256, 0, stream>>>(
            xb, w1b, b1, tok, cnt, act);
        fc2_mfma<<<dim3(H_DIM / 128, E_NUM * 32), 256, 0, stream>>>(
            act, w2b, b2, cnt, ybuf);
        combine_kernel<<<T_TOK, 256, 0, stream>>>(ybuf, tidx, twgt, cnt, out);
        return;
    }

    // fp32 fallback (round-1 proven)
    size_t actB = (size_t)ACT_CAP_F * I_DIM * 2;
    ushort_t* act = (ushort_t*)ws;
    char* p = ws + actB;
    int*    tok  = (int*)p;     p += tok_sz;
    float*  wgt  = (float*)p;   p += tok_sz;
    int4*   tidx = (int4*)p;    p += tidx_sz;
    float2* twgt = (float2*)p;  p += twgt_sz;
    int*    cnt  = (int*)p;
    int*    cnt_pad = cnt + E_NUM;
    int*    off  = cnt_pad + E_NUM;
    size_t need = actB + 2 * tok_sz + tidx_sz + twgt_sz + 256;
    if (ws_size < need) return;

    hipMemsetAsync(cnt, 0, E_NUM * sizeof(int), stream);
    hipMemsetAsync(d_out, 0, (size_t)T_TOK * H_DIM * sizeof(float), stream);
    gate_fb<<<T_TOK, 64, 0, stream>>>(x, gw, tok, wgt, tidx, twgt, cnt);
    pad_kernel<<<1, 256, 0, stream>>>(tok, wgt, cnt, cnt_pad, off, TILE_M);
    fc1_kernel<<<dim3(I_DIM / 64, E_NUM * 64), 256, 0, stream>>>(
        x, w1, b1, tok, cnt_pad, off, act);
    fc2_kernel<<<dim3(H_DIM / 64, E_NUM * 64), 256, 0, stream>>>(
        act, w2, b2, tok, wgt, cnt_pad, off, out);
}

// Round 3
// 842.196 us; speedup vs baseline: 1.1203x; 1.0047x over previous
//
#include <hip/hip_runtime.h>
#include <math.h>

// SwigluMoE routed, round 7: 5-dispatch pipeline.
//   memset(tok,cnt) -> prep(gate + x->bf16 + w1/w2->bf16) -> fc1 -> fc2 -> combine
// R7 change vs R6: prep's cvt section was WG-DISPATCH-RATE limited, not
// memory limited (evidence: R0 2-deep coalesced and R2 8-deep uncoalesced
// both ~1.8 TB/s with all pipes idle and occupancy stuck at 40% despite
// VGPR=56/no-LDS). 13312 one-shot ~1us workgroups need ~1500 WG/us dispatch
// to keep CUs fed; SPI can't. Fix per G11: 1024 LONG-LIVED cvt blocks, each
// 12 chunk-iterations of 8 coalesced float4 loads + 8 ushort4 stores.
// combine: 4 tokens/block -> 1024 blocks (same principle).
// fc1/fc2: m97-style global_load_lds BK=64 bf16 MFMA (unchanged).
// T=4096, H=2048, I=2048 (2I=4096), E=8, top-2. Routed = 206 GFLOP.

#define T_TOK 4096
#define H_DIM 2048
#define I_DIM 2048
#define F_DIM 4096   // 2*I
#define E_NUM 8
#define ALPHA_C 1.702f
#define ALPHA_LOG2E 2.4554674f   // 1.702 * log2(e)

// fp32 fallback tiling
#define TILE_M 64
#define KT 32
#define ACT_CAP_F (2 * T_TOK + E_NUM * TILE_M)   // 8704
// bf16 path tiling
#define BTM 128
#define ACT_CAP_B (2 * T_TOK + E_NUM * BTM)      // 9216

#define GATE_BLOCKS (T_TOK / 4)   // 1024
#define CVT_BLOCKS 1024           // long-lived, grid-stride over chunks
#define CHUNK_F4 2048             // float4s per chunk (256 thr x 8)
#define NCHUNK 12288              // (w1+w2 float4s)/CHUNK_F4 = 25165824/2048
#define W1_CHUNKS 8192            // w1 float4s / CHUNK_F4
#define W1_F4 16777216            // w1 float4 count
#define CVT_ITERS (NCHUNK / CVT_BLOCKS)   // 12, exact

typedef unsigned short ushort_t;
typedef __attribute__((ext_vector_type(8))) unsigned short ushort8v;
typedef __attribute__((ext_vector_type(8))) __bf16 bf16x8;
typedef __attribute__((ext_vector_type(4))) float f32x4;

__device__ __forceinline__ ushort_t f2bf(float f) {
    unsigned int u = __float_as_uint(f);
    unsigned int r = (u + 0x7FFFu + ((u >> 16) & 1u)) >> 16;  // RNE
    return (ushort_t)r;
}
__device__ __forceinline__ float bf2f(ushort_t b) {
    return __uint_as_float(((unsigned int)b) << 16);
}

__device__ __forceinline__ void gl_lds16(const ushort_t* g, ushort_t* l) {
    __builtin_amdgcn_global_load_lds(
        (const __attribute__((address_space(1))) void*)g,
        (__attribute__((address_space(3))) void*)l, 16, 0, 0);
}

// ---------------------------------------------------------------- prep ------
// blocks [0, GATE_BLOCKS): gating (4 tokens/block, 1 wave each) + x->bf16.
// blocks [GATE_BLOCKS, +CVT_BLOCKS): w1||w2 -> bf16.
//   Each block: 12 chunks of 2048 float4; per chunk, thread t does 8 coalesced
//   float4 loads at stride 256*16B and 8 coalesced ushort4 stores.
__global__ __launch_bounds__(256) void prep_kernel(
    const float* __restrict__ x, const float* __restrict__ gw,
    const float* __restrict__ w1, const float* __restrict__ w2,
    ushort_t* __restrict__ wb, ushort_t* __restrict__ xb,
    int* __restrict__ tok, int4* __restrict__ tidx, float2* __restrict__ twgt,
    int* __restrict__ cnt) {
    if (blockIdx.x < GATE_BLOCKS) {
        int t = blockIdx.x * 4 + (threadIdx.x >> 6);
        int lane = threadIdx.x & 63;
        const float* xr = x + (size_t)t * H_DIM;
        ushort_t* xbr = xb + (size_t)t * H_DIM;
        float acc[E_NUM];
#pragma unroll
        for (int e = 0; e < E_NUM; e++) acc[e] = 0.f;
#pragma unroll
        for (int i = 0; i < H_DIM / 256; i++) {
            int j = (i * 64 + lane) * 4;
            float4 xv = *(const float4*)(xr + j);
            *(ushort4*)(xbr + j) =
                make_ushort4(f2bf(xv.x), f2bf(xv.y), f2bf(xv.z), f2bf(xv.w));
#pragma unroll
            for (int e = 0; e < E_NUM; e++) {
                float4 g = *(const float4*)(gw + e * H_DIM + j);
                acc[e] += xv.x * g.x + xv.y * g.y + xv.z * g.z + xv.w * g.w;
            }
        }
#pragma unroll
        for (int e = 0; e < E_NUM; e++) {
#pragma unroll
            for (int s = 32; s > 0; s >>= 1) acc[e] += __shfl_xor(acc[e], s, 64);
        }
        if (lane == 0) {
            int i0 = 0; float b0 = acc[0];
            for (int e = 1; e < E_NUM; e++) if (acc[e] > b0) { b0 = acc[e]; i0 = e; }
            int i1 = -1; float b1 = -3.0e38f;
            for (int e = 0; e < E_NUM; e++) {
                if (e == i0) continue;
                if (acc[e] > b1) { b1 = acc[e]; i1 = e; }
            }
            float e10 = expf(b1 - b0);
            float w0 = 1.f / (1.f + e10);
            float w1v = 1.f - w0;
            int p0 = atomicAdd(&cnt[i0], 1);
            tok[i0 * T_TOK + p0] = t;
            int p1 = atomicAdd(&cnt[i1], 1);
            tok[i1 * T_TOK + p1] = t;
            tidx[t] = make_int4(i0, p0, i1, p1);
            twgt[t] = make_float2(w0, w1v);
        }
    } else {
        int bid = (int)blockIdx.x - GATE_BLOCKS;   // 0..1023
        int tid = (int)threadIdx.x;
        for (int i = 0; i < CVT_ITERS; i++) {
            int c = bid + i * CVT_BLOCKS;               // chunk id 0..12287
            size_t g0 = (size_t)c * CHUNK_F4 + tid;     // float4 index base
            const float* s = (c < W1_CHUNKS)
                                 ? (w1 + g0 * 4)
                                 : (w2 + (g0 - (size_t)W1_F4) * 4);
            ushort_t* d = wb + g0 * 4;
            f32x4 v[8];
#pragma unroll
            for (int j = 0; j < 8; j++)
                v[j] = *(const f32x4*)(s + (size_t)j * 1024);   // 256 f4 stride
#pragma unroll
            for (int j = 0; j < 8; j++) {
                *(ushort4*)(d + (size_t)j * 1024) = make_ushort4(
                    f2bf(v[j][0]), f2bf(v[j][1]), f2bf(v[j][2]), f2bf(v[j][3]));
            }
        }
    }
}

// helper: padded count prefix from cnt[] (8 L2-hot loads, wave-uniform)
__device__ __forceinline__ void calc_off(const int* __restrict__ cnt, int e,
                                         int& off_e, int& cpad_e) {
    int o = 0, cp = 0;
#pragma unroll
    for (int q = 0; q < E_NUM; q++) {
        int c = (cnt[q] + BTM - 1) & ~(BTM - 1);
        if (q < e) o += c;
        if (q == e) cp = c;
    }
    off_e = o; cpad_e = cp;
}

// ============================ bf16 MFMA path ================================
// fc1: 128 pair-rows x 64 i (=128 f rows, g/l split tiles). BK=64 as two
// 32-wide sub-tiles (64B row stride: 2-way LDS aliasing free; keeps
// global_load_lds contiguous-lane layout). 4 waves, 2x2.
__global__ __launch_bounds__(256, 3) void fc1_mfma(
    const ushort_t* __restrict__ xb, const ushort_t* __restrict__ w1b,
    const float* __restrict__ b1, const int* __restrict__ tok,
    const int* __restrict__ cnt, ushort_t* __restrict__ act) {
    int e = blockIdx.y >> 5;
    int tile = blockIdx.y & 31;
    int off_e, cpad_e;
    calc_off(cnt, e, off_e, cpad_e);
    if (tile * BTM >= cpad_e) return;
    int i0 = blockIdx.x * 64;

    __shared__ ushort_t As[2][128 * 32];
    __shared__ ushort_t Bg[2][64 * 32];
    __shared__ ushort_t Bl[2][64 * 32];

    int tid = threadIdx.x;
    int lane = tid & 63;
    int ww = tid >> 6;
    int wm = ww & 1, wn = ww >> 1;
    int l15 = lane & 15, quad = lane >> 4;
    int r4 = lane >> 2;           // 0..15
    int koff = (lane & 3) * 8;    // 0,8,16,24

    const int* tlist = tok + e * T_TOK + tile * BTM;
    int ar0 = ww * 32 + r4;
    const ushort_t* a0 = xb + (size_t)tlist[ar0] * H_DIM + koff;
    const ushort_t* a1 = xb + (size_t)tlist[ar0 + 16] * H_DIM + koff;
    int il = ww * 16 + r4;
    const ushort_t* bsrc = w1b + ((size_t)e * F_DIM + 2 * (i0 + il)) * H_DIM + koff;

    ushort_t* ad0a = &As[0][(ww * 32) * 32];
    ushort_t* ad0b = &As[0][(ww * 32 + 16) * 32];
    ushort_t* ad1a = &As[1][(ww * 32) * 32];
    ushort_t* ad1b = &As[1][(ww * 32 + 16) * 32];
    ushort_t* bg0 = &Bg[0][(ww * 16) * 32];
    ushort_t* bg1 = &Bg[1][(ww * 16) * 32];
    ushort_t* bl0 = &Bl[0][(ww * 16) * 32];
    ushort_t* bl1 = &Bl[1][(ww * 16) * 32];

    f32x4 zf = {0.f, 0.f, 0.f, 0.f};
    f32x4 accg[4][2], accl[4][2];
#pragma unroll
    for (int mc = 0; mc < 4; mc++)
#pragma unroll
        for (int nc = 0; nc < 2; nc++) { accg[mc][nc] = zf; accl[mc][nc] = zf; }

    for (int k0 = 0; k0 < H_DIM; k0 += 64) {
        __syncthreads();
        gl_lds16(a0, ad0a);
        gl_lds16(a1, ad0b);
        gl_lds16(a0 + 32, ad1a);
        gl_lds16(a1 + 32, ad1b);
        gl_lds16(bsrc, bg0);
        gl_lds16(bsrc + 32, bg1);
        gl_lds16(bsrc + H_DIM, bl0);
        gl_lds16(bsrc + H_DIM + 32, bl1);
        a0 += 64; a1 += 64; bsrc += 64;
        __syncthreads();

#pragma unroll
        for (int kk = 0; kk < 2; kk++) {
            bf16x8 af[4], bgf[2], blf[2];
#pragma unroll
            for (int mc = 0; mc < 4; mc++)
                af[mc] = *(const bf16x8*)&As[kk][(wm * 64 + mc * 16 + l15) * 32 + quad * 8];
#pragma unroll
            for (int nc = 0; nc < 2; nc++) {
                bgf[nc] = *(const bf16x8*)&Bg[kk][(wn * 32 + nc * 16 + l15) * 32 + quad * 8];
                blf[nc] = *(const bf16x8*)&Bl[kk][(wn * 32 + nc * 16 + l15) * 32 + quad * 8];
            }
#pragma unroll
            for (int mc = 0; mc < 4; mc++)
#pragma unroll
                for (int nc = 0; nc < 2; nc++) {
                    accg[mc][nc] = __builtin_amdgcn_mfma_f32_16x16x32_bf16(
                        af[mc], bgf[nc], accg[mc][nc], 0, 0, 0);
                    accl[mc][nc] = __builtin_amdgcn_mfma_f32_16x16x32_bf16(
                        af[mc], blf[nc], accl[mc][nc], 0, 0, 0);
                }
        }
    }

    // epilogue: bias + swiglu (fast sigmoid), act bf16. D: row=quad*4+r, col=l15.
    int rowbase = off_e + tile * BTM + wm * 64;
    int colbase = i0 + wn * 32;
    float bgc[2], blc[2];
#pragma unroll
    for (int nc = 0; nc < 2; nc++) {
        int i = colbase + nc * 16 + l15;
        bgc[nc] = b1[(size_t)e * F_DIM + 2 * i];
        blc[nc] = b1[(size_t)e * F_DIM + 2 * i + 1];
    }
#pragma unroll
    for (int mc = 0; mc < 4; mc++)
#pragma unroll
        for (int nc = 0; nc < 2; nc++) {
            int i = colbase + nc * 16 + l15;
#pragma unroll
            for (int r = 0; r < 4; r++) {
                int m = rowbase + mc * 16 + quad * 4 + r;
                float g = accg[mc][nc][r] + bgc[nc];
                float l = accl[mc][nc][r] + blc[nc];
                float s = __builtin_amdgcn_rcpf(
                    1.f + __builtin_amdgcn_exp2f(-ALPHA_LOG2E * g));
                act[(size_t)m * I_DIM + i] = f2bf(g * s * (l + 1.f));
            }
        }
}

// fc2: 128 pair-rows x 128 h, BK=64 split sub-tiles. Writes ybuf bf16
// (bias fused); combine gathers per token (no atomics).
__global__ __launch_bounds__(256, 3) void fc2_mfma(
    const ushort_t* __restrict__ act, const ushort_t* __restrict__ w2b,
    const float* __restrict__ b2, const int* __restrict__ cnt,
    ushort_t* __restrict__ ybuf) {
    int e = blockIdx.y >> 5;
    int tile = blockIdx.y & 31;
    int off_e, cpad_e;
    calc_off(cnt, e, off_e, cpad_e);
    if (tile * BTM >= cpad_e) return;
    int h0 = blockIdx.x * 128;
    int rowbase = off_e + tile * BTM;

    __shared__ ushort_t As[2][128 * 32];
    __shared__ ushort_t Bs[2][128 * 32];

    int tid = threadIdx.x;
    int lane = tid & 63;
    int ww = tid >> 6;
    int wm = ww & 1, wn = ww >> 1;
    int l15 = lane & 15, quad = lane >> 4;
    int r4 = lane >> 2;
    int koff = (lane & 3) * 8;

    int ar = ww * 32 + r4;
    const ushort_t* a0 = act + (size_t)(rowbase + ar) * I_DIM + koff;
    const ushort_t* a1 = a0 + (size_t)16 * I_DIM;
    const ushort_t* b0 = w2b + ((size_t)e * H_DIM + h0 + ar) * I_DIM + koff;
    const ushort_t* b1p = b0 + (size_t)16 * I_DIM;

    ushort_t* ad0a = &As[0][(ww * 32) * 32];
    ushort_t* ad0b = &As[0][(ww * 32 + 16) * 32];
    ushort_t* ad1a = &As[1][(ww * 32) * 32];
    ushort_t* ad1b = &As[1][(ww * 32 + 16) * 32];
    ushort_t* bd0a = &Bs[0][(ww * 32) * 32];
    ushort_t* bd0b = &Bs[0][(ww * 32 + 16) * 32];
    ushort_t* bd1a = &Bs[1][(ww * 32) * 32];
    ushort_t* bd1b = &Bs[1][(ww * 32 + 16) * 32];

    f32x4 zf = {0.f, 0.f, 0.f, 0.f};
    f32x4 acc[4][4];
#pragma unroll
    for (int mc = 0; mc < 4; mc++)
#pragma unroll
        for (int nc = 0; nc < 4; nc++) acc[mc][nc] = zf;

    for (int k0 = 0; k0 < I_DIM; k0 += 64) {
        __syncthreads();
        gl_lds16(a0, ad0a);
        gl_lds16(a1, ad0b);
        gl_lds16(a0 + 32, ad1a);
        gl_lds16(a1 + 32, ad1b);
        gl_lds16(b0, bd0a);
        gl_lds16(b1p, bd0b);
        gl_lds16(b0 + 32, bd1a);
        gl_lds16(b1p + 32, bd1b);
        a0 += 64; a1 += 64; b0 += 64; b1p += 64;
        __syncthreads();

#pragma unroll
        for (int kk = 0; kk < 2; kk++) {
            bf16x8 af[4], bf[4];
#pragma unroll
            for (int mc = 0; mc < 4; mc++)
                af[mc] = *(const bf16x8*)&As[kk][(wm * 64 + mc * 16 + l15) * 32 + quad * 8];
#pragma unroll
            for (int nc = 0; nc < 4; nc++)
                bf[nc] = *(const bf16x8*)&Bs[kk][(wn * 64 + nc * 16 + l15) * 32 + quad * 8];
#pragma unroll
            for (int mc = 0; mc < 4; mc++)
#pragma unroll
                for (int nc = 0; nc < 4; nc++)
                    acc[mc][nc] = __builtin_amdgcn_mfma_f32_16x16x32_bf16(
                        af[mc], bf[nc], acc[mc][nc], 0, 0, 0);
        }
    }

    float bc[4];
#pragma unroll
    for (int nc = 0; nc < 4; nc++)
        bc[nc] = b2[(size_t)e * H_DIM + h0 + wn * 64 + nc * 16 + l15];
#pragma unroll
    for (int mc = 0; mc < 4; mc++)
#pragma unroll
        for (int nc = 0; nc < 4; nc++) {
            int h = h0 + wn * 64 + nc * 16 + l15;
#pragma unroll
            for (int r = 0; r < 4; r++) {
                int m = rowbase + wm * 64 + mc * 16 + quad * 4 + r;
                ybuf[(size_t)m * H_DIM + h] = f2bf(acc[mc][nc][r] + bc[nc]);
            }
        }
}

// combine: out[t] = w0*y[row(e0,p0)] + w1*y[row(e1,p1)]; 4 tokens per block.
__global__ __launch_bounds__(256) void combine_kernel(
    const ushort_t* __restrict__ ybuf, const int4* __restrict__ tidx,
    const float2* __restrict__ twgt, const int* __restrict__ cnt,
    float* __restrict__ out) {
    int offv[E_NUM];
    {
        int o = 0;
#pragma unroll
        for (int q = 0; q < E_NUM; q++) {
            offv[q] = o;
            o += (cnt[q] + BTM - 1) & ~(BTM - 1);
        }
    }
    int h = threadIdx.x * 8;
#pragma unroll
    for (int tt = 0; tt < 4; tt++) {
        int t = blockIdx.x * 4 + tt;
        int4 idx = tidx[t];
        float2 w = twgt[t];
        size_t r0 = (size_t)offv[idx.x] + idx.y;
        size_t r1 = (size_t)offv[idx.z] + idx.w;
        ushort8v a = *(const ushort8v*)(ybuf + r0 * H_DIM + h);
        ushort8v b = *(const ushort8v*)(ybuf + r1 * H_DIM + h);
        float* op = out + (size_t)t * H_DIM + h;
#pragma unroll
        for (int q = 0; q < 8; q++)
            op[q] = w.x * bf2f(a[q]) + w.y * bf2f(b[q]);
    }
}

// ============================ fp32 fallback path ============================
__global__ __launch_bounds__(64) void gate_fb(
    const float* __restrict__ x, const float* __restrict__ gw,
    int* __restrict__ tok, float* __restrict__ wgt,
    int4* __restrict__ tidx, float2* __restrict__ twgt, int* __restrict__ cnt) {
    int t = blockIdx.x;
    int lane = threadIdx.x;
    const float* xr = x + (size_t)t * H_DIM;
    float acc[E_NUM];
#pragma unroll
    for (int e = 0; e < E_NUM; e++) acc[e] = 0.f;
    for (int j = lane; j < H_DIM; j += 64) {
        float xv = xr[j];
#pragma unroll
        for (int e = 0; e < E_NUM; e++) acc[e] += xv * gw[e * H_DIM + j];
    }
#pragma unroll
    for (int e = 0; e < E_NUM; e++) {
#pragma unroll
        for (int s = 32; s > 0; s >>= 1) acc[e] += __shfl_xor(acc[e], s, 64);
    }
    if (lane == 0) {
        int i0 = 0; float b0 = acc[0];
        for (int e = 1; e < E_NUM; e++) if (acc[e] > b0) { b0 = acc[e]; i0 = e; }
        int i1 = -1; float b1 = -3.0e38f;
        for (int e = 0; e < E_NUM; e++) {
            if (e == i0) continue;
            if (acc[e] > b1) { b1 = acc[e]; i1 = e; }
        }
        float e10 = expf(b1 - b0);
        float w0 = 1.f / (1.f + e10);
        float w1 = 1.f - w0;
        int p0 = atomicAdd(&cnt[i0], 1);
        tok[i0 * T_TOK + p0] = t; wgt[i0 * T_TOK + p0] = w0;
        int p1 = atomicAdd(&cnt[i1], 1);
        tok[i1 * T_TOK + p1] = t; wgt[i1 * T_TOK + p1] = w1;
        tidx[t] = make_int4(i0, p0, i1, p1);
        twgt[t] = make_float2(w0, w1);
    }
}

__global__ __launch_bounds__(256) void pad_kernel(
    int* __restrict__ tok, float* __restrict__ wgt,
    const int* __restrict__ cnt, int* __restrict__ cnt_pad,
    int* __restrict__ off, int tile) {
    __shared__ int s_cnt[E_NUM], s_pad[E_NUM];
    if (threadIdx.x == 0) {
        int o = 0;
        for (int e = 0; e < E_NUM; e++) {
            int c = cnt[e];
            int cp = (c + tile - 1) / tile * tile;
            s_cnt[e] = c; s_pad[e] = cp;
            cnt_pad[e] = cp;
            off[e] = o;
            o += cp;
        }
    }
    __syncthreads();
    for (int e = 0; e < E_NUM; e++) {
        for (int p = s_cnt[e] + (int)threadIdx.x; p < s_pad[e]; p += 256) {
            tok[e * T_TOK + p] = 0;
            wgt[e * T_TOK + p] = 0.f;
        }
    }
}

__global__ __launch_bounds__(256) void fc1_kernel(
    const float* __restrict__ x, const float* __restrict__ w1,
    const float* __restrict__ b1, const int* __restrict__ tok,
    const int* __restrict__ cnt_pad, const int* __restrict__ off,
    ushort_t* __restrict__ act) {
    int e = blockIdx.y >> 6;
    int tile = blockIdx.y & 63;
    if (tile * TILE_M >= cnt_pad[e]) return;
    int i0 = blockIdx.x * 64;
    int f0 = i0 * 2;

    __shared__ float xs[KT][TILE_M + 4];
    __shared__ float wsh[KT][128 + 4];

    int tid = threadIdx.x;
    int tx = tid & 15, ty = tid >> 4;
    int rloc = tid >> 3;
    int c4 = (tid & 7) * 4;

    const int* tlist = tok + e * T_TOK + tile * TILE_M;
    int tk0 = tlist[rloc];
    int tk1 = tlist[rloc + 32];
    const float* xp0 = x + (size_t)tk0 * H_DIM + c4;
    const float* xp1 = x + (size_t)tk1 * H_DIM + c4;
    const float* wp = w1 + ((size_t)e * F_DIM + f0 + rloc) * H_DIM + c4;

    float ga[4][4] = {{0.f}}, la[4][4] = {{0.f}};

    for (int k0 = 0; k0 < H_DIM; k0 += KT) {
        __syncthreads();
        {
            float4 v0 = *(const float4*)(xp0 + k0);
            float4 v1 = *(const float4*)(xp1 + k0);
            xs[c4 + 0][rloc] = v0.x; xs[c4 + 1][rloc] = v0.y;
            xs[c4 + 2][rloc] = v0.z; xs[c4 + 3][rloc] = v0.w;
            xs[c4 + 0][rloc + 32] = v1.x; xs[c4 + 1][rloc + 32] = v1.y;
            xs[c4 + 2][rloc + 32] = v1.z; xs[c4 + 3][rloc + 32] = v1.w;
        }
        {
#pragma unroll
            for (int r = 0; r < 4; r++) {
                float4 v = *(const float4*)(wp + (size_t)(32 * r) * H_DIM + k0);
                int fr = rloc + 32 * r;
                wsh[c4 + 0][fr] = v.x; wsh[c4 + 1][fr] = v.y;
                wsh[c4 + 2][fr] = v.z; wsh[c4 + 3][fr] = v.w;
            }
        }
        __syncthreads();
#pragma unroll
        for (int k = 0; k < KT; k++) {
            float4 xv = *(const float4*)&xs[k][ty * 4];
            float4 wa = *(const float4*)&wsh[k][tx * 8];
            float4 wb = *(const float4*)&wsh[k][tx * 8 + 4];
            float xm[4] = {xv.x, xv.y, xv.z, xv.w};
            float gg[4] = {wa.x, wa.z, wb.x, wb.z};
            float ll[4] = {wa.y, wa.w, wb.y, wb.w};
#pragma unroll
            for (int m = 0; m < 4; m++)
#pragma unroll
                for (int n = 0; n < 4; n++) {
                    ga[m][n] += xm[m] * gg[n];
                    la[m][n] += xm[m] * ll[n];
                }
        }
    }

    int rowbase = off[e] + tile * TILE_M;
    float bg[4], bl[4];
#pragma unroll
    for (int n = 0; n < 4; n++) {
        int i = i0 + tx * 4 + n;
        bg[n] = b1[(size_t)e * F_DIM + 2 * i];
        bl[n] = b1[(size_t)e * F_DIM + 2 * i + 1];
    }
#pragma unroll
    for (int m = 0; m < 4; m++) {
        int row = rowbase + ty * 4 + m;
        ushort_t us[4];
#pragma unroll
        for (int n = 0; n < 4; n++) {
            float g = ga[m][n] + bg[n];
            float l = la[m][n] + bl[n];
            float s = 1.f / (1.f + expf(-ALPHA_C * g));
            us[n] = f2bf(g * s * (l + 1.f));
        }
        *(ushort4*)&act[(size_t)row * I_DIM + i0 + tx * 4] =
            make_ushort4(us[0], us[1], us[2], us[3]);
    }
}

__global__ __launch_bounds__(256) void fc2_kernel(
    const ushort_t* __restrict__ act, const float* __restrict__ w2,
    const float* __restrict__ b2, const int* __restrict__ tok,
    const float* __restrict__ wgt, const int* __restrict__ cnt_pad,
    const int* __restrict__ off, float* __restrict__ out) {
    int e = blockIdx.y >> 6;
    int tile = blockIdx.y & 63;
    if (tile * TILE_M >= cnt_pad[e]) return;
    int h0 = blockIdx.x * 64;

    __shared__ float as_[KT][TILE_M + 4];
    __shared__ float wsh[KT][64 + 4];

    int tid = threadIdx.x;
    int tx = tid & 15, ty = tid >> 4;
    int rowbase = off[e] + tile * TILE_M;

    int arow = tid >> 2;
    int ac8 = (tid & 3) * 8;
    const ushort_t* ap = act + (size_t)(rowbase + arow) * I_DIM + ac8;
    int rloc = tid >> 3;
    int c4 = (tid & 7) * 4;
    const float* wp = w2 + ((size_t)e * H_DIM + h0 + rloc) * I_DIM + c4;

    float acc[4][4] = {{0.f}};

    for (int k0 = 0; k0 < I_DIM; k0 += KT) {
        __syncthreads();
        {
            ushort8v v = *(const ushort8v*)(ap + k0);
#pragma unroll
            for (int q = 0; q < 8; q++) as_[ac8 + q][arow] = bf2f(v[q]);
        }
        {
#pragma unroll
            for (int r = 0; r < 2; r++) {
                float4 v = *(const float4*)(wp + (size_t)(32 * r) * I_DIM + k0);
                int hr = rloc + 32 * r;
                wsh[c4 + 0][hr] = v.x; wsh[c4 + 1][hr] = v.y;
                wsh[c4 + 2][hr] = v.z; wsh[c4 + 3][hr] = v.w;
            }
        }
        __syncthreads();
#pragma unroll
        for (int k = 0; k < KT; k++) {
            float4 xv = *(const float4*)&as_[k][ty * 4];
            float4 wv = *(const float4*)&wsh[k][tx * 4];
            float xm[4] = {xv.x, xv.y, xv.z, xv.w};
            float wn[4] = {wv.x, wv.y, wv.z, wv.w};
#pragma unroll
            for (int m = 0; m < 4; m++)
#pragma unroll
                for (int n = 0; n < 4; n++) acc[m][n] += xm[m] * wn[n];
        }
    }

    const int* tlist = tok + e * T_TOK + tile * TILE_M;
    const float* wlist = wgt + e * T_TOK + tile * TILE_M;
#pragma unroll
    for (int m = 0; m < 4; m++) {
        int row = ty * 4 + m;
        int t = tlist[row];
        float w = wlist[row];
        if (w == 0.f) continue;
#pragma unroll
        for (int n = 0; n < 4; n++) {
            int h = h0 + tx * 4 + n;
            float y = acc[m][n] + b2[(size_t)e * H_DIM + h];
            atomicAdd(out + (size_t)t * H_DIM + h, w * y);
        }
    }
}

// --------------------------------------------------------------- launch -----
extern "C" void kernel_launch(void* const* d_in, const int* in_sizes, int n_in,
                              void* d_out, int out_size, void* d_ws, size_t ws_size,
                              hipStream_t stream) {
    const float* x  = (const float*)d_in[0];
    const float* gw = (const float*)d_in[1];
    const float* w1 = (const float*)d_in[2];
    const float* b1 = (const float*)d_in[3];
    const float* w2 = (const float*)d_in[4];
    const float* b2 = (const float*)d_in[5];
    float* out = (float*)d_out;
    char* ws = (char*)d_ws;

    size_t w1b_sz = (size_t)E_NUM * F_DIM * H_DIM * 2;  // 134217728
    size_t w2b_sz = (size_t)E_NUM * H_DIM * I_DIM * 2;  // 67108864
    size_t xb_sz  = (size_t)T_TOK * H_DIM * 2;          // 16777216
    size_t act_sz = (size_t)ACT_CAP_B * I_DIM * 2;      // 37748736
    size_t tok_sz = (size_t)E_NUM * T_TOK * 4;          // 131072
    size_t tidx_sz = (size_t)T_TOK * 16;
    size_t twgt_sz = (size_t)T_TOK * 8;
    size_t need_big = w1b_sz + w2b_sz + xb_sz + act_sz + tok_sz + 64 +
                      tidx_sz + twgt_sz + 256;

    if (ws_size >= need_big) {
        ushort_t* w1b = (ushort_t*)ws;                       // also ybuf later
        ushort_t* w2b = (ushort_t*)(ws + w1b_sz);
        ushort_t* xb  = (ushort_t*)(ws + w1b_sz + w2b_sz);
        ushort_t* act = (ushort_t*)(ws + w1b_sz + w2b_sz + xb_sz);
        char* p = ws + w1b_sz + w2b_sz + xb_sz + act_sz;
        int*    tok  = (int*)p;                 p += tok_sz;
        int*    cnt  = (int*)p;                 p += 64;   // adjacent to tok
        int4*   tidx = (int4*)p;                p += tidx_sz;
        float2* twgt = (float2*)p;
        ushort_t* ybuf = w1b;   // w1b dead after fc1

        // zero tok lists + cnt in one shot: padding = token 0 for free
        hipMemsetAsync(tok, 0, tok_sz + 64, stream);
        prep_kernel<<<GATE_BLOCKS + CVT_BLOCKS, 256, 0, stream>>>(
            x, gw, w1, w2, w1b, xb, tok, tidx, twgt, cnt);
        fc1_mfma<<<dim3(I_DIM / 64, E_NUM * 32), 256, 0, stream>>>(
            xb, w1b, b1, tok, cnt, act);
        fc2_mfma<<<dim3(H_DIM / 128, E_NUM * 32), 256, 0, stream>>>(
            act, w2b, b2, cnt, ybuf);
        combine_kernel<<<T_TOK / 4, 256, 0, stream>>>(ybuf, tidx, twgt, cnt, out);
        return;
    }

    // fp32 fallback (round-1 proven)
    size_t actB = (size_t)ACT_CAP_F * I_DIM * 2;
    ushort_t* act = (ushort_t*)ws;
    char* p = ws + actB;
    int*    tok  = (int*)p;     p += tok_sz;
    float*  wgt  = (float*)p;   p += tok_sz;
    int4*   tidx = (int4*)p;    p += tidx_sz;
    float2* twgt = (float2*)p;  p += twgt_sz;
    int*    cnt  = (int*)p;
    int*    cnt_pad = cnt + E_NUM;
    int*    off  = cnt_pad + E_NUM;
    size_t need = actB + 2 * tok_sz + tidx_sz + twgt_sz + 256;
    if (ws_size < need) return;

    hipMemsetAsync(cnt, 0, E_NUM * sizeof(int), stream);
    hipMemsetAsync(d_out, 0, (size_t)T_TOK * H_DIM * sizeof(float), stream);
    gate_fb<<<T_TOK, 64, 0, stream>>>(x, gw, tok, wgt, tidx, twgt, cnt);
    pad_kernel<<<1, 256, 0, stream>>>(tok, wgt, cnt, cnt_pad, off, TILE_M);
    fc1_kernel<<<dim3(I_DIM / 64, E_NUM * 64), 256, 0, stream>>>(
        x, w1, b1, tok, cnt_pad, off, act);
    fc2_kernel<<<dim3(H_DIM / 64, E_NUM * 64), 256, 0, stream>>>(
        act, w2, b2, tok, wgt, cnt_pad, off, out);
}

// Round 4
// 791.273 us; speedup vs baseline: 1.1924x; 1.0644x over previous
//
#include <hip/hip_runtime.h>
#include <math.h>

// SwigluMoE routed, round 8: 7-dispatch pipeline, atomic-free routing.
//   memset(tok,cnt) -> gate -> route -> cvt -> fc1 -> fc2 -> combine
// R8 theory: prep's invariant ~230us across 3 cvt restructurings was the
// GATE's same-cache-line atomic storm: 8192 atomicAdd-with-return on cnt[8]
// (one 32B line), all arriving at once from 4096 waves; ~28ns/serialized RMW
// = ~230us. Fix: deterministic routing.
//   * gate_kernel: logits + top-2 + x->bf16, writes tidx(i0,_,i1,_)+twgt,
//     ZERO atomics.
//   * route_kernel: 8 blocks (1/expert), ballot+popc prefix compaction over
//     4096 tokens -> tok lists, p0/p1 back into tidx.y/.w, cnt[e]. ~10us.
//   * cvt_kernel: w1||w2 -> bf16, 2048 long-lived blocks, isolated counters.
// Split also gives per-phase rocprof rows (ablation discipline).
// fc1/fc2: m97-style global_load_lds BK=64 bf16 MFMA (unchanged).
// T=4096, H=2048, I=2048 (2I=4096), E=8, top-2. Routed = 206 GFLOP.

#define T_TOK 4096
#define H_DIM 2048
#define I_DIM 2048
#define F_DIM 4096   // 2*I
#define E_NUM 8
#define ALPHA_C 1.702f
#define ALPHA_LOG2E 2.4554674f   // 1.702 * log2(e)

// fp32 fallback tiling
#define TILE_M 64
#define KT 32
#define ACT_CAP_F (2 * T_TOK + E_NUM * TILE_M)   // 8704
// bf16 path tiling
#define BTM 128
#define ACT_CAP_B (2 * T_TOK + E_NUM * BTM)      // 9216

#define GATE_BLOCKS (T_TOK / 4)   // 1024
#define CHUNK_F4 2048             // float4s per chunk (256 thr x 8)
#define NCHUNK 12288              // (w1+w2 float4s)/CHUNK_F4
#define W1_CHUNKS 8192            // w1 float4s / CHUNK_F4
#define W1_F4 16777216            // w1 float4 count
#define CVT_BLOCKS 2048           // long-lived
#define CVT_ITERS (NCHUNK / CVT_BLOCKS)   // 6, exact

typedef unsigned short ushort_t;
typedef __attribute__((ext_vector_type(8))) unsigned short ushort8v;
typedef __attribute__((ext_vector_type(8))) __bf16 bf16x8;
typedef __attribute__((ext_vector_type(4))) float f32x4;

__device__ __forceinline__ ushort_t f2bf(float f) {
    unsigned int u = __float_as_uint(f);
    unsigned int r = (u + 0x7FFFu + ((u >> 16) & 1u)) >> 16;  // RNE
    return (ushort_t)r;
}
__device__ __forceinline__ float bf2f(ushort_t b) {
    return __uint_as_float(((unsigned int)b) << 16);
}

__device__ __forceinline__ void gl_lds16(const ushort_t* g, ushort_t* l) {
    __builtin_amdgcn_global_load_lds(
        (const __attribute__((address_space(1))) void*)g,
        (__attribute__((address_space(3))) void*)l, 16, 0, 0);
}

// ---------------------------------------------------------------- gate ------
// 4 tokens/block, 1 wave each: logits vs 8 experts + x->bf16. No atomics:
// writes tidx[t]=(i0,_,i1,_) and twgt[t]; route_kernel assigns positions.
__global__ __launch_bounds__(256) void gate_kernel(
    const float* __restrict__ x, const float* __restrict__ gw,
    ushort_t* __restrict__ xb, int4* __restrict__ tidx,
    float2* __restrict__ twgt) {
    int t = blockIdx.x * 4 + (threadIdx.x >> 6);
    int lane = threadIdx.x & 63;
    const float* xr = x + (size_t)t * H_DIM;
    ushort_t* xbr = xb + (size_t)t * H_DIM;
    float acc[E_NUM];
#pragma unroll
    for (int e = 0; e < E_NUM; e++) acc[e] = 0.f;
#pragma unroll
    for (int i = 0; i < H_DIM / 256; i++) {
        int j = (i * 64 + lane) * 4;
        float4 xv = *(const float4*)(xr + j);
        *(ushort4*)(xbr + j) =
            make_ushort4(f2bf(xv.x), f2bf(xv.y), f2bf(xv.z), f2bf(xv.w));
#pragma unroll
        for (int e = 0; e < E_NUM; e++) {
            float4 g = *(const float4*)(gw + e * H_DIM + j);
            acc[e] += xv.x * g.x + xv.y * g.y + xv.z * g.z + xv.w * g.w;
        }
    }
#pragma unroll
    for (int e = 0; e < E_NUM; e++) {
#pragma unroll
        for (int s = 32; s > 0; s >>= 1) acc[e] += __shfl_xor(acc[e], s, 64);
    }
    if (lane == 0) {
        int i0 = 0; float b0 = acc[0];
        for (int e = 1; e < E_NUM; e++) if (acc[e] > b0) { b0 = acc[e]; i0 = e; }
        int i1 = -1; float b1 = -3.0e38f;
        for (int e = 0; e < E_NUM; e++) {
            if (e == i0) continue;
            if (acc[e] > b1) { b1 = acc[e]; i1 = e; }
        }
        float e10 = expf(b1 - b0);
        float w0 = 1.f / (1.f + e10);
        float w1v = 1.f - w0;
        tidx[t] = make_int4(i0, 0, i1, 0);
        twgt[t] = make_float2(w0, w1v);
    }
}

// ---------------------------------------------------------------- route -----
// 8 blocks (one per expert), deterministic prefix compaction, no atomics.
// Block e scans all tokens in order; matching tokens get ascending positions.
// Writes tok[e*T_TOK+p]=t, tidx[t].y/.w=p, cnt[e]. Fields .y/.w of a given
// token are each written by exactly one block (i0 != i1).
__global__ __launch_bounds__(256) void route_kernel(
    const int4* tidx_ro, int* tidx_w, int* __restrict__ tok,
    int* __restrict__ cnt) {
    int e = blockIdx.x;
    int tid = threadIdx.x;
    int lane = tid & 63;
    int wv = tid >> 6;
    __shared__ int wsum[4];
    __shared__ int sbase;
    if (tid == 0) sbase = 0;
    __syncthreads();
    for (int c = 0; c < T_TOK / 256; c++) {
        int t = c * 256 + tid;
        int4 v = tidx_ro[t];
        bool fA = (v.x == e);
        bool fB = (v.z == e);
        bool f = fA || fB;
        unsigned long long m = __ballot(f);
        int my = __popcll(m & ((1ull << lane) - 1ull));
        int wt = __popcll(m);
        if (lane == 0) wsum[wv] = wt;
        __syncthreads();
        int woff = 0;
#pragma unroll
        for (int q = 0; q < 4; q++) woff += (q < wv) ? wsum[q] : 0;
        int tot = wsum[0] + wsum[1] + wsum[2] + wsum[3];
        int base = sbase;
        if (f) {
            int p = base + woff + my;
            tok[e * T_TOK + p] = t;
            tidx_w[t * 4 + (fA ? 1 : 3)] = p;
        }
        __syncthreads();
        if (tid == 0) sbase = base + tot;
        __syncthreads();
    }
    if (tid == 0) cnt[e] = sbase;
}

// ---------------------------------------------------------------- cvt -------
// w1||w2 -> bf16. 2048 long-lived blocks x 6 chunks; per chunk thread does
// 8 coalesced float4 loads (stride 256 f4) + 8 coalesced ushort4 stores.
__global__ __launch_bounds__(256) void cvt_kernel(
    const float* __restrict__ w1, const float* __restrict__ w2,
    ushort_t* __restrict__ wb) {
    int bid = (int)blockIdx.x;
    int tid = (int)threadIdx.x;
    for (int i = 0; i < CVT_ITERS; i++) {
        int c = bid + i * CVT_BLOCKS;               // chunk id 0..12287
        size_t g0 = (size_t)c * CHUNK_F4 + tid;     // float4 index base
        const float* s = (c < W1_CHUNKS)
                             ? (w1 + g0 * 4)
                             : (w2 + (g0 - (size_t)W1_F4) * 4);
        ushort_t* d = wb + g0 * 4;
        f32x4 v[8];
#pragma unroll
        for (int j = 0; j < 8; j++)
            v[j] = *(const f32x4*)(s + (size_t)j * 1024);   // 256 f4 stride
#pragma unroll
        for (int j = 0; j < 8; j++) {
            *(ushort4*)(d + (size_t)j * 1024) = make_ushort4(
                f2bf(v[j][0]), f2bf(v[j][1]), f2bf(v[j][2]), f2bf(v[j][3]));
        }
    }
}

// helper: padded count prefix from cnt[] (8 L2-hot loads, wave-uniform)
__device__ __forceinline__ void calc_off(const int* __restrict__ cnt, int e,
                                         int& off_e, int& cpad_e) {
    int o = 0, cp = 0;
#pragma unroll
    for (int q = 0; q < E_NUM; q++) {
        int c = (cnt[q] + BTM - 1) & ~(BTM - 1);
        if (q < e) o += c;
        if (q == e) cp = c;
    }
    off_e = o; cpad_e = cp;
}

// ============================ bf16 MFMA path ================================
// fc1: 128 pair-rows x 64 i (=128 f rows, g/l split tiles). BK=64 as two
// 32-wide sub-tiles (64B row stride: 2-way LDS aliasing free; keeps
// global_load_lds contiguous-lane layout). 4 waves, 2x2.
__global__ __launch_bounds__(256, 3) void fc1_mfma(
    const ushort_t* __restrict__ xb, const ushort_t* __restrict__ w1b,
    const float* __restrict__ b1, const int* __restrict__ tok,
    const int* __restrict__ cnt, ushort_t* __restrict__ act) {
    int e = blockIdx.y >> 5;
    int tile = blockIdx.y & 31;
    int off_e, cpad_e;
    calc_off(cnt, e, off_e, cpad_e);
    if (tile * BTM >= cpad_e) return;
    int i0 = blockIdx.x * 64;

    __shared__ ushort_t As[2][128 * 32];
    __shared__ ushort_t Bg[2][64 * 32];
    __shared__ ushort_t Bl[2][64 * 32];

    int tid = threadIdx.x;
    int lane = tid & 63;
    int ww = tid >> 6;
    int wm = ww & 1, wn = ww >> 1;
    int l15 = lane & 15, quad = lane >> 4;
    int r4 = lane >> 2;           // 0..15
    int koff = (lane & 3) * 8;    // 0,8,16,24

    const int* tlist = tok + e * T_TOK + tile * BTM;
    int ar0 = ww * 32 + r4;
    const ushort_t* a0 = xb + (size_t)tlist[ar0] * H_DIM + koff;
    const ushort_t* a1 = xb + (size_t)tlist[ar0 + 16] * H_DIM + koff;
    int il = ww * 16 + r4;
    const ushort_t* bsrc = w1b + ((size_t)e * F_DIM + 2 * (i0 + il)) * H_DIM + koff;

    ushort_t* ad0a = &As[0][(ww * 32) * 32];
    ushort_t* ad0b = &As[0][(ww * 32 + 16) * 32];
    ushort_t* ad1a = &As[1][(ww * 32) * 32];
    ushort_t* ad1b = &As[1][(ww * 32 + 16) * 32];
    ushort_t* bg0 = &Bg[0][(ww * 16) * 32];
    ushort_t* bg1 = &Bg[1][(ww * 16) * 32];
    ushort_t* bl0 = &Bl[0][(ww * 16) * 32];
    ushort_t* bl1 = &Bl[1][(ww * 16) * 32];

    f32x4 zf = {0.f, 0.f, 0.f, 0.f};
    f32x4 accg[4][2], accl[4][2];
#pragma unroll
    for (int mc = 0; mc < 4; mc++)
#pragma unroll
        for (int nc = 0; nc < 2; nc++) { accg[mc][nc] = zf; accl[mc][nc] = zf; }

    for (int k0 = 0; k0 < H_DIM; k0 += 64) {
        __syncthreads();
        gl_lds16(a0, ad0a);
        gl_lds16(a1, ad0b);
        gl_lds16(a0 + 32, ad1a);
        gl_lds16(a1 + 32, ad1b);
        gl_lds16(bsrc, bg0);
        gl_lds16(bsrc + 32, bg1);
        gl_lds16(bsrc + H_DIM, bl0);
        gl_lds16(bsrc + H_DIM + 32, bl1);
        a0 += 64; a1 += 64; bsrc += 64;
        __syncthreads();

#pragma unroll
        for (int kk = 0; kk < 2; kk++) {
            bf16x8 af[4], bgf[2], blf[2];
#pragma unroll
            for (int mc = 0; mc < 4; mc++)
                af[mc] = *(const bf16x8*)&As[kk][(wm * 64 + mc * 16 + l15) * 32 + quad * 8];
#pragma unroll
            for (int nc = 0; nc < 2; nc++) {
                bgf[nc] = *(const bf16x8*)&Bg[kk][(wn * 32 + nc * 16 + l15) * 32 + quad * 8];
                blf[nc] = *(const bf16x8*)&Bl[kk][(wn * 32 + nc * 16 + l15) * 32 + quad * 8];
            }
#pragma unroll
            for (int mc = 0; mc < 4; mc++)
#pragma unroll
                for (int nc = 0; nc < 2; nc++) {
                    accg[mc][nc] = __builtin_amdgcn_mfma_f32_16x16x32_bf16(
                        af[mc], bgf[nc], accg[mc][nc], 0, 0, 0);
                    accl[mc][nc] = __builtin_amdgcn_mfma_f32_16x16x32_bf16(
                        af[mc], blf[nc], accl[mc][nc], 0, 0, 0);
                }
        }
    }

    // epilogue: bias + swiglu (fast sigmoid), act bf16. D: row=quad*4+r, col=l15.
    int rowbase = off_e + tile * BTM + wm * 64;
    int colbase = i0 + wn * 32;
    float bgc[2], blc[2];
#pragma unroll
    for (int nc = 0; nc < 2; nc++) {
        int i = colbase + nc * 16 + l15;
        bgc[nc] = b1[(size_t)e * F_DIM + 2 * i];
        blc[nc] = b1[(size_t)e * F_DIM + 2 * i + 1];
    }
#pragma unroll
    for (int mc = 0; mc < 4; mc++)
#pragma unroll
        for (int nc = 0; nc < 2; nc++) {
            int i = colbase + nc * 16 + l15;
#pragma unroll
            for (int r = 0; r < 4; r++) {
                int m = rowbase + mc * 16 + quad * 4 + r;
                float g = accg[mc][nc][r] + bgc[nc];
                float l = accl[mc][nc][r] + blc[nc];
                float s = __builtin_amdgcn_rcpf(
                    1.f + __builtin_amdgcn_exp2f(-ALPHA_LOG2E * g));
                act[(size_t)m * I_DIM + i] = f2bf(g * s * (l + 1.f));
            }
        }
}

// fc2: 128 pair-rows x 128 h, BK=64 split sub-tiles. Writes ybuf bf16
// (bias fused); combine gathers per token (no atomics).
__global__ __launch_bounds__(256, 3) void fc2_mfma(
    const ushort_t* __restrict__ act, const ushort_t* __restrict__ w2b,
    const float* __restrict__ b2, const int* __restrict__ cnt,
    ushort_t* __restrict__ ybuf) {
    int e = blockIdx.y >> 5;
    int tile = blockIdx.y & 31;
    int off_e, cpad_e;
    calc_off(cnt, e, off_e, cpad_e);
    if (tile * BTM >= cpad_e) return;
    int h0 = blockIdx.x * 128;
    int rowbase = off_e + tile * BTM;

    __shared__ ushort_t As[2][128 * 32];
    __shared__ ushort_t Bs[2][128 * 32];

    int tid = threadIdx.x;
    int lane = tid & 63;
    int ww = tid >> 6;
    int wm = ww & 1, wn = ww >> 1;
    int l15 = lane & 15, quad = lane >> 4;
    int r4 = lane >> 2;
    int koff = (lane & 3) * 8;

    int ar = ww * 32 + r4;
    const ushort_t* a0 = act + (size_t)(rowbase + ar) * I_DIM + koff;
    const ushort_t* a1 = a0 + (size_t)16 * I_DIM;
    const ushort_t* b0 = w2b + ((size_t)e * H_DIM + h0 + ar) * I_DIM + koff;
    const ushort_t* b1p = b0 + (size_t)16 * I_DIM;

    ushort_t* ad0a = &As[0][(ww * 32) * 32];
    ushort_t* ad0b = &As[0][(ww * 32 + 16) * 32];
    ushort_t* ad1a = &As[1][(ww * 32) * 32];
    ushort_t* ad1b = &As[1][(ww * 32 + 16) * 32];
    ushort_t* bd0a = &Bs[0][(ww * 32) * 32];
    ushort_t* bd0b = &Bs[0][(ww * 32 + 16) * 32];
    ushort_t* bd1a = &Bs[1][(ww * 32) * 32];
    ushort_t* bd1b = &Bs[1][(ww * 32 + 16) * 32];

    f32x4 zf = {0.f, 0.f, 0.f, 0.f};
    f32x4 acc[4][4];
#pragma unroll
    for (int mc = 0; mc < 4; mc++)
#pragma unroll
        for (int nc = 0; nc < 4; nc++) acc[mc][nc] = zf;

    for (int k0 = 0; k0 < I_DIM; k0 += 64) {
        __syncthreads();
        gl_lds16(a0, ad0a);
        gl_lds16(a1, ad0b);
        gl_lds16(a0 + 32, ad1a);
        gl_lds16(a1 + 32, ad1b);
        gl_lds16(b0, bd0a);
        gl_lds16(b1p, bd0b);
        gl_lds16(b0 + 32, bd1a);
        gl_lds16(b1p + 32, bd1b);
        a0 += 64; a1 += 64; b0 += 64; b1p += 64;
        __syncthreads();

#pragma unroll
        for (int kk = 0; kk < 2; kk++) {
            bf16x8 af[4], bf[4];
#pragma unroll
            for (int mc = 0; mc < 4; mc++)
                af[mc] = *(const bf16x8*)&As[kk][(wm * 64 + mc * 16 + l15) * 32 + quad * 8];
#pragma unroll
            for (int nc = 0; nc < 4; nc++)
                bf[nc] = *(const bf16x8*)&Bs[kk][(wn * 64 + nc * 16 + l15) * 32 + quad * 8];
#pragma unroll
            for (int mc = 0; mc < 4; mc++)
#pragma unroll
                for (int nc = 0; nc < 4; nc++)
                    acc[mc][nc] = __builtin_amdgcn_mfma_f32_16x16x32_bf16(
                        af[mc], bf[nc], acc[mc][nc], 0, 0, 0);
        }
    }

    float bc[4];
#pragma unroll
    for (int nc = 0; nc < 4; nc++)
        bc[nc] = b2[(size_t)e * H_DIM + h0 + wn * 64 + nc * 16 + l15];
#pragma unroll
    for (int mc = 0; mc < 4; mc++)
#pragma unroll
        for (int nc = 0; nc < 4; nc++) {
            int h = h0 + wn * 64 + nc * 16 + l15;
#pragma unroll
            for (int r = 0; r < 4; r++) {
                int m = rowbase + wm * 64 + mc * 16 + quad * 4 + r;
                ybuf[(size_t)m * H_DIM + h] = f2bf(acc[mc][nc][r] + bc[nc]);
            }
        }
}

// combine: out[t] = w0*y[row(e0,p0)] + w1*y[row(e1,p1)]; 4 tokens per block.
__global__ __launch_bounds__(256) void combine_kernel(
    const ushort_t* __restrict__ ybuf, const int4* __restrict__ tidx,
    const float2* __restrict__ twgt, const int* __restrict__ cnt,
    float* __restrict__ out) {
    int offv[E_NUM];
    {
        int o = 0;
#pragma unroll
        for (int q = 0; q < E_NUM; q++) {
            offv[q] = o;
            o += (cnt[q] + BTM - 1) & ~(BTM - 1);
        }
    }
    int h = threadIdx.x * 8;
#pragma unroll
    for (int tt = 0; tt < 4; tt++) {
        int t = blockIdx.x * 4 + tt;
        int4 idx = tidx[t];
        float2 w = twgt[t];
        size_t r0 = (size_t)offv[idx.x] + idx.y;
        size_t r1 = (size_t)offv[idx.z] + idx.w;
        ushort8v a = *(const ushort8v*)(ybuf + r0 * H_DIM + h);
        ushort8v b = *(const ushort8v*)(ybuf + r1 * H_DIM + h);
        float* op = out + (size_t)t * H_DIM + h;
#pragma unroll
        for (int q = 0; q < 8; q++)
            op[q] = w.x * bf2f(a[q]) + w.y * bf2f(b[q]);
    }
}

// ============================ fp32 fallback path ============================
__global__ __launch_bounds__(64) void gate_fb(
    const float* __restrict__ x, const float* __restrict__ gw,
    int* __restrict__ tok, float* __restrict__ wgt,
    int4* __restrict__ tidx, float2* __restrict__ twgt, int* __restrict__ cnt) {
    int t = blockIdx.x;
    int lane = threadIdx.x;
    const float* xr = x + (size_t)t * H_DIM;
    float acc[E_NUM];
#pragma unroll
    for (int e = 0; e < E_NUM; e++) acc[e] = 0.f;
    for (int j = lane; j < H_DIM; j += 64) {
        float xv = xr[j];
#pragma unroll
        for (int e = 0; e < E_NUM; e++) acc[e] += xv * gw[e * H_DIM + j];
    }
#pragma unroll
    for (int e = 0; e < E_NUM; e++) {
#pragma unroll
        for (int s = 32; s > 0; s >>= 1) acc[e] += __shfl_xor(acc[e], s, 64);
    }
    if (lane == 0) {
        int i0 = 0; float b0 = acc[0];
        for (int e = 1; e < E_NUM; e++) if (acc[e] > b0) { b0 = acc[e]; i0 = e; }
        int i1 = -1; float b1 = -3.0e38f;
        for (int e = 0; e < E_NUM; e++) {
            if (e == i0) continue;
            if (acc[e] > b1) { b1 = acc[e]; i1 = e; }
        }
        float e10 = expf(b1 - b0);
        float w0 = 1.f / (1.f + e10);
        float w1 = 1.f - w0;
        int p0 = atomicAdd(&cnt[i0], 1);
        tok[i0 * T_TOK + p0] = t; wgt[i0 * T_TOK + p0] = w0;
        int p1 = atomicAdd(&cnt[i1], 1);
        tok[i1 * T_TOK + p1] = t; wgt[i1 * T_TOK + p1] = w1;
        tidx[t] = make_int4(i0, p0, i1, p1);
        twgt[t] = make_float2(w0, w1);
    }
}

__global__ __launch_bounds__(256) void pad_kernel(
    int* __restrict__ tok, float* __restrict__ wgt,
    const int* __restrict__ cnt, int* __restrict__ cnt_pad,
    int* __restrict__ off, int tile) {
    __shared__ int s_cnt[E_NUM], s_pad[E_NUM];
    if (threadIdx.x == 0) {
        int o = 0;
        for (int e = 0; e < E_NUM; e++) {
            int c = cnt[e];
            int cp = (c + tile - 1) / tile * tile;
            s_cnt[e] = c; s_pad[e] = cp;
            cnt_pad[e] = cp;
            off[e] = o;
            o += cp;
        }
    }
    __syncthreads();
    for (int e = 0; e < E_NUM; e++) {
        for (int p = s_cnt[e] + (int)threadIdx.x; p < s_pad[e]; p += 256) {
            tok[e * T_TOK + p] = 0;
            wgt[e * T_TOK + p] = 0.f;
        }
    }
}

__global__ __launch_bounds__(256) void fc1_kernel(
    const float* __restrict__ x, const float* __restrict__ w1,
    const float* __restrict__ b1, const int* __restrict__ tok,
    const int* __restrict__ cnt_pad, const int* __restrict__ off,
    ushort_t* __restrict__ act) {
    int e = blockIdx.y >> 6;
    int tile = blockIdx.y & 63;
    if (tile * TILE_M >= cnt_pad[e]) return;
    int i0 = blockIdx.x * 64;
    int f0 = i0 * 2;

    __shared__ float xs[KT][TILE_M + 4];
    __shared__ float wsh[KT][128 + 4];

    int tid = threadIdx.x;
    int tx = tid & 15, ty = tid >> 4;
    int rloc = tid >> 3;
    int c4 = (tid & 7) * 4;

    const int* tlist = tok + e * T_TOK + tile * TILE_M;
    int tk0 = tlist[rloc];
    int tk1 = tlist[rloc + 32];
    const float* xp0 = x + (size_t)tk0 * H_DIM + c4;
    const float* xp1 = x + (size_t)tk1 * H_DIM + c4;
    const float* wp = w1 + ((size_t)e * F_DIM + f0 + rloc) * H_DIM + c4;

    float ga[4][4] = {{0.f}}, la[4][4] = {{0.f}};

    for (int k0 = 0; k0 < H_DIM; k0 += KT) {
        __syncthreads();
        {
            float4 v0 = *(const float4*)(xp0 + k0);
            float4 v1 = *(const float4*)(xp1 + k0);
            xs[c4 + 0][rloc] = v0.x; xs[c4 + 1][rloc] = v0.y;
            xs[c4 + 2][rloc] = v0.z; xs[c4 + 3][rloc] = v0.w;
            xs[c4 + 0][rloc + 32] = v1.x; xs[c4 + 1][rloc + 32] = v1.y;
            xs[c4 + 2][rloc + 32] = v1.z; xs[c4 + 3][rloc + 32] = v1.w;
        }
        {
#pragma unroll
            for (int r = 0; r < 4; r++) {
                float4 v = *(const float4*)(wp + (size_t)(32 * r) * H_DIM + k0);
                int fr = rloc + 32 * r;
                wsh[c4 + 0][fr] = v.x; wsh[c4 + 1][fr] = v.y;
                wsh[c4 + 2][fr] = v.z; wsh[c4 + 3][fr] = v.w;
            }
        }
        __syncthreads();
#pragma unroll
        for (int k = 0; k < KT; k++) {
            float4 xv = *(const float4*)&xs[k][ty * 4];
            float4 wa = *(const float4*)&wsh[k][tx * 8];
            float4 wb = *(const float4*)&wsh[k][tx * 8 + 4];
            float xm[4] = {xv.x, xv.y, xv.z, xv.w};
            float gg[4] = {wa.x, wa.z, wb.x, wb.z};
            float ll[4] = {wa.y, wa.w, wb.y, wb.w};
#pragma unroll
            for (int m = 0; m < 4; m++)
#pragma unroll
                for (int n = 0; n < 4; n++) {
                    ga[m][n] += xm[m] * gg[n];
                    la[m][n] += xm[m] * ll[n];
                }
        }
    }

    int rowbase = off[e] + tile * TILE_M;
    float bg[4], bl[4];
#pragma unroll
    for (int n = 0; n < 4; n++) {
        int i = i0 + tx * 4 + n;
        bg[n] = b1[(size_t)e * F_DIM + 2 * i];
        bl[n] = b1[(size_t)e * F_DIM + 2 * i + 1];
    }
#pragma unroll
    for (int m = 0; m < 4; m++) {
        int row = rowbase + ty * 4 + m;
        ushort_t us[4];
#pragma unroll
        for (int n = 0; n < 4; n++) {
            float g = ga[m][n] + bg[n];
            float l = la[m][n] + bl[n];
            float s = 1.f / (1.f + expf(-ALPHA_C * g));
            us[n] = f2bf(g * s * (l + 1.f));
        }
        *(ushort4*)&act[(size_t)row * I_DIM + i0 + tx * 4] =
            make_ushort4(us[0], us[1], us[2], us[3]);
    }
}

__global__ __launch_bounds__(256) void fc2_kernel(
    const ushort_t* __restrict__ act, const float* __restrict__ w2,
    const float* __restrict__ b2, const int* __restrict__ tok,
    const float* __restrict__ wgt, const int* __restrict__ cnt_pad,
    const int* __restrict__ off, float* __restrict__ out) {
    int e = blockIdx.y >> 6;
    int tile = blockIdx.y & 63;
    if (tile * TILE_M >= cnt_pad[e]) return;
    int h0 = blockIdx.x * 64;

    __shared__ float as_[KT][TILE_M + 4];
    __shared__ float wsh[KT][64 + 4];

    int tid = threadIdx.x;
    int tx = tid & 15, ty = tid >> 4;
    int rowbase = off[e] + tile * TILE_M;

    int arow = tid >> 2;
    int ac8 = (tid & 3) * 8;
    const ushort_t* ap = act + (size_t)(rowbase + arow) * I_DIM + ac8;
    int rloc = tid >> 3;
    int c4 = (tid & 7) * 4;
    const float* wp = w2 + ((size_t)e * H_DIM + h0 + rloc) * I_DIM + c4;

    float acc[4][4] = {{0.f}};

    for (int k0 = 0; k0 < I_DIM; k0 += KT) {
        __syncthreads();
        {
            ushort8v v = *(const ushort8v*)(ap + k0);
#pragma unroll
            for (int q = 0; q < 8; q++) as_[ac8 + q][arow] = bf2f(v[q]);
        }
        {
#pragma unroll
            for (int r = 0; r < 2; r++) {
                float4 v = *(const float4*)(wp + (size_t)(32 * r) * I_DIM + k0);
                int hr = rloc + 32 * r;
                wsh[c4 + 0][hr] = v.x; wsh[c4 + 1][hr] = v.y;
                wsh[c4 + 2][hr] = v.z; wsh[c4 + 3][hr] = v.w;
            }
        }
        __syncthreads();
#pragma unroll
        for (int k = 0; k < KT; k++) {
            float4 xv = *(const float4*)&as_[k][ty * 4];
            float4 wv = *(const float4*)&wsh[k][tx * 4];
            float xm[4] = {xv.x, xv.y, xv.z, xv.w};
            float wn[4] = {wv.x, wv.y, wv.z, wv.w};
#pragma unroll
            for (int m = 0; m < 4; m++)
#pragma unroll
                for (int n = 0; n < 4; n++) acc[m][n] += xm[m] * wn[n];
        }
    }

    const int* tlist = tok + e * T_TOK + tile * TILE_M;
    const float* wlist = wgt + e * T_TOK + tile * TILE_M;
#pragma unroll
    for (int m = 0; m < 4; m++) {
        int row = ty * 4 + m;
        int t = tlist[row];
        float w = wlist[row];
        if (w == 0.f) continue;
#pragma unroll
        for (int n = 0; n < 4; n++) {
            int h = h0 + tx * 4 + n;
            float y = acc[m][n] + b2[(size_t)e * H_DIM + h];
            atomicAdd(out + (size_t)t * H_DIM + h, w * y);
        }
    }
}

// --------------------------------------------------------------- launch -----
extern "C" void kernel_launch(void* const* d_in, const int* in_sizes, int n_in,
                              void* d_out, int out_size, void* d_ws, size_t ws_size,
                              hipStream_t stream) {
    const float* x  = (const float*)d_in[0];
    const float* gw = (const float*)d_in[1];
    const float* w1 = (const float*)d_in[2];
    const float* b1 = (const float*)d_in[3];
    const float* w2 = (const float*)d_in[4];
    const float* b2 = (const float*)d_in[5];
    float* out = (float*)d_out;
    char* ws = (char*)d_ws;

    size_t w1b_sz = (size_t)E_NUM * F_DIM * H_DIM * 2;  // 134217728
    size_t w2b_sz = (size_t)E_NUM * H_DIM * I_DIM * 2;  // 67108864
    size_t xb_sz  = (size_t)T_TOK * H_DIM * 2;          // 16777216
    size_t act_sz = (size_t)ACT_CAP_B * I_DIM * 2;      // 37748736
    size_t tok_sz = (size_t)E_NUM * T_TOK * 4;          // 131072
    size_t tidx_sz = (size_t)T_TOK * 16;
    size_t twgt_sz = (size_t)T_TOK * 8;
    size_t need_big = w1b_sz + w2b_sz + xb_sz + act_sz + tok_sz + 64 +
                      tidx_sz + twgt_sz + 256;

    if (ws_size >= need_big) {
        ushort_t* w1b = (ushort_t*)ws;                       // also ybuf later
        ushort_t* w2b = (ushort_t*)(ws + w1b_sz);
        ushort_t* xb  = (ushort_t*)(ws + w1b_sz + w2b_sz);
        ushort_t* act = (ushort_t*)(ws + w1b_sz + w2b_sz + xb_sz);
        char* p = ws + w1b_sz + w2b_sz + xb_sz + act_sz;
        int*    tok  = (int*)p;                 p += tok_sz;
        int*    cnt  = (int*)p;                 p += 64;   // adjacent to tok
        int4*   tidx = (int4*)p;                p += tidx_sz;
        float2* twgt = (float2*)p;
        ushort_t* ybuf = w1b;   // w1b dead after fc1

        // zero tok lists (+cnt region): padding = token 0 for free
        hipMemsetAsync(tok, 0, tok_sz + 64, stream);
        gate_kernel<<<GATE_BLOCKS, 256, 0, stream>>>(x, gw, xb, tidx, twgt);
        route_kernel<<<E_NUM, 256, 0, stream>>>(
            (const int4*)tidx, (int*)tidx, tok, cnt);
        cvt_kernel<<<CVT_BLOCKS, 256, 0, stream>>>(w1, w2, w1b);
        fc1_mfma<<<dim3(I_DIM / 64, E_NUM * 32), 256, 0, stream>>>(
            xb, w1b, b1, tok, cnt, act);
        fc2_mfma<<<dim3(H_DIM / 128, E_NUM * 32), 256, 0, stream>>>(
            act, w2b, b2, cnt, ybuf);
        combine_kernel<<<T_TOK / 4, 256, 0, stream>>>(ybuf, tidx, twgt, cnt, out);
        return;
    }

    // fp32 fallback (round-1 proven)
    size_t actB = (size_t)ACT_CAP_F * I_DIM * 2;
    ushort_t* act = (ushort_t*)ws;
    char* p = ws + actB;
    int*    tok  = (int*)p;     p += tok_sz;
    float*  wgt  = (float*)p;   p += tok_sz;
    int4*   tidx = (int4*)p;    p += tidx_sz;
    float2* twgt = (float2*)p;  p += twgt_sz;
    int*    cnt  = (int*)p;
    int*    cnt_pad = cnt + E_NUM;
    int*    off  = cnt_pad + E_NUM;
    size_t need = actB + 2 * tok_sz + tidx_sz + twgt_sz + 256;
    if (ws_size < need) return;

    hipMemsetAsync(cnt, 0, E_NUM * sizeof(int), stream);
    hipMemsetAsync(d_out, 0, (size_t)T_TOK * H_DIM * sizeof(float), stream);
    gate_fb<<<T_TOK, 64, 0, stream>>>(x, gw, tok, wgt, tidx, twgt, cnt);
    pad_kernel<<<1, 256, 0, stream>>>(tok, wgt, cnt, cnt_pad, off, TILE_M);
    fc1_kernel<<<dim3(I_DIM / 64, E_NUM * 64), 256, 0, stream>>>(
        x, w1, b1, tok, cnt_pad, off, act);
    fc2_kernel<<<dim3(H_DIM / 64, E_NUM * 64), 256, 0, stream>>>(
        act, w2, b2, tok, wgt, cnt_pad, off, out);
}

// Round 5
// 765.913 us; speedup vs baseline: 1.2319x; 1.0331x over previous
//
#include <hip/hip_runtime.h>
#include <math.h>

// SwigluMoE routed, round 9: 6-dispatch overlapped pipeline.
//   memset(tok) -> gate(+w1cvt riders) -> route -> fc1(+w2cvt riders)
//   -> fc2 -> combine
// R9 changes vs R8 (791us; fc1 186us top, MfmaUtil 33% ~= m97 ceiling):
//   * w1->bf16 conversion rides in the GATE dispatch (independent work;
//     memory-only waves co-schedule with gate's compute, m114)
//   * w2->bf16 conversion rides in the FC1 dispatch (fc1 at 17% HBM has
//     ~5TB/s headroom; w2b needed only by fc2). R1's rider regression was
//     confounded by NT loads - retried clean.
//   * fc1/fc2 grids compacted: grid.y = 72 tiles over PADDED ROW SPACE
//     (each block derives (e,tile) from cnt prefix) - kills the ~5900
//     early-return block flood per dispatch.
// fc1/fc2 core: m97-style global_load_lds BK=64 bf16 MFMA (unchanged).
// T=4096, H=2048, I=2048 (2I=4096), E=8, top-2. Routed = 206 GFLOP.

#define T_TOK 4096
#define H_DIM 2048
#define I_DIM 2048
#define F_DIM 4096   // 2*I
#define E_NUM 8
#define ALPHA_C 1.702f
#define ALPHA_LOG2E 2.4554674f   // 1.702 * log2(e)

// fp32 fallback tiling
#define TILE_M 64
#define KT 32
#define ACT_CAP_F (2 * T_TOK + E_NUM * TILE_M)   // 8704
// bf16 path tiling
#define BTM 128
#define ACT_CAP_B (2 * T_TOK + E_NUM * BTM)      // 9216
#define TILES_Y (ACT_CAP_B / BTM)                // 72 padded-row tiles

#define GATE_BLOCKS (T_TOK / 4)   // 1024
#define CHUNK_F4 2048             // float4s per chunk (256 thr x 8)
// w1: 16777216 f4 -> 8192 chunks; riders in gate dispatch
#define W1_CHUNKS 8192
#define CVT1_BLOCKS 2048
#define CVT1_ITERS 4
// w2: 8388608 f4 -> 4096 chunks; riders in fc1 dispatch
#define W2_CHUNKS 4096
#define W2X 16                    // rider grid.x columns in fc1

typedef unsigned short ushort_t;
typedef __attribute__((ext_vector_type(8))) unsigned short ushort8v;
typedef __attribute__((ext_vector_type(8))) __bf16 bf16x8;
typedef __attribute__((ext_vector_type(4))) float f32x4;

__device__ __forceinline__ ushort_t f2bf(float f) {
    unsigned int u = __float_as_uint(f);
    unsigned int r = (u + 0x7FFFu + ((u >> 16) & 1u)) >> 16;  // RNE
    return (ushort_t)r;
}
__device__ __forceinline__ float bf2f(ushort_t b) {
    return __uint_as_float(((unsigned int)b) << 16);
}

__device__ __forceinline__ void gl_lds16(const ushort_t* g, ushort_t* l) {
    __builtin_amdgcn_global_load_lds(
        (const __attribute__((address_space(1))) void*)g,
        (__attribute__((address_space(3))) void*)l, 16, 0, 0);
}

// convert one 2048-f4 chunk: thread does 8 coalesced float4 loads
// (stride 256 f4) + 8 coalesced ushort4 stores.
__device__ __forceinline__ void cvt_chunk(const float* __restrict__ s,
                                          ushort_t* __restrict__ d) {
    f32x4 v[8];
#pragma unroll
    for (int j = 0; j < 8; j++)
        v[j] = *(const f32x4*)(s + (size_t)j * 1024);
#pragma unroll
    for (int j = 0; j < 8; j++) {
        *(ushort4*)(d + (size_t)j * 1024) = make_ushort4(
            f2bf(v[j][0]), f2bf(v[j][1]), f2bf(v[j][2]), f2bf(v[j][3]));
    }
}

// ---------------------------------------------------------------- gate ------
// blocks [0,1024): 4 tokens/block, 1 wave each: logits + x->bf16; writes
// tidx(i0,_,i1,_)+twgt, NO atomics. blocks [1024,3072): w1->bf16 riders.
__global__ __launch_bounds__(256) void gate_kernel(
    const float* __restrict__ x, const float* __restrict__ gw,
    const float* __restrict__ w1, ushort_t* __restrict__ w1b,
    ushort_t* __restrict__ xb, int4* __restrict__ tidx,
    float2* __restrict__ twgt) {
    if (blockIdx.x >= GATE_BLOCKS) {
        int bid = (int)blockIdx.x - GATE_BLOCKS;
        int tid = (int)threadIdx.x;
#pragma unroll
        for (int i = 0; i < CVT1_ITERS; i++) {
            int c = bid + i * CVT1_BLOCKS;
            size_t g0 = (size_t)c * CHUNK_F4 + tid;
            cvt_chunk(w1 + g0 * 4, w1b + g0 * 4);
        }
        return;
    }
    int t = blockIdx.x * 4 + (threadIdx.x >> 6);
    int lane = threadIdx.x & 63;
    const float* xr = x + (size_t)t * H_DIM;
    ushort_t* xbr = xb + (size_t)t * H_DIM;
    float acc[E_NUM];
#pragma unroll
    for (int e = 0; e < E_NUM; e++) acc[e] = 0.f;
#pragma unroll
    for (int i = 0; i < H_DIM / 256; i++) {
        int j = (i * 64 + lane) * 4;
        float4 xv = *(const float4*)(xr + j);
        *(ushort4*)(xbr + j) =
            make_ushort4(f2bf(xv.x), f2bf(xv.y), f2bf(xv.z), f2bf(xv.w));
#pragma unroll
        for (int e = 0; e < E_NUM; e++) {
            float4 g = *(const float4*)(gw + e * H_DIM + j);
            acc[e] += xv.x * g.x + xv.y * g.y + xv.z * g.z + xv.w * g.w;
        }
    }
#pragma unroll
    for (int e = 0; e < E_NUM; e++) {
#pragma unroll
        for (int s = 32; s > 0; s >>= 1) acc[e] += __shfl_xor(acc[e], s, 64);
    }
    if (lane == 0) {
        int i0 = 0; float b0 = acc[0];
        for (int e = 1; e < E_NUM; e++) if (acc[e] > b0) { b0 = acc[e]; i0 = e; }
        int i1 = -1; float b1 = -3.0e38f;
        for (int e = 0; e < E_NUM; e++) {
            if (e == i0) continue;
            if (acc[e] > b1) { b1 = acc[e]; i1 = e; }
        }
        float e10 = expf(b1 - b0);
        float w0 = 1.f / (1.f + e10);
        float w1v = 1.f - w0;
        tidx[t] = make_int4(i0, 0, i1, 0);
        twgt[t] = make_float2(w0, w1v);
    }
}

// ---------------------------------------------------------------- route -----
// 8 blocks (one per expert), deterministic prefix compaction, no atomics.
__global__ __launch_bounds__(256) void route_kernel(
    const int4* tidx_ro, int* tidx_w, int* __restrict__ tok,
    int* __restrict__ cnt) {
    int e = blockIdx.x;
    int tid = threadIdx.x;
    int lane = tid & 63;
    int wv = tid >> 6;
    __shared__ int wsum[4];
    __shared__ int sbase;
    if (tid == 0) sbase = 0;
    __syncthreads();
    for (int c = 0; c < T_TOK / 256; c++) {
        int t = c * 256 + tid;
        int4 v = tidx_ro[t];
        bool fA = (v.x == e);
        bool fB = (v.z == e);
        bool f = fA || fB;
        unsigned long long m = __ballot(f);
        int my = __popcll(m & ((1ull << lane) - 1ull));
        int wt = __popcll(m);
        if (lane == 0) wsum[wv] = wt;
        __syncthreads();
        int woff = 0;
#pragma unroll
        for (int q = 0; q < 4; q++) woff += (q < wv) ? wsum[q] : 0;
        int tot = wsum[0] + wsum[1] + wsum[2] + wsum[3];
        int base = sbase;
        if (f) {
            int p = base + woff + my;
            tok[e * T_TOK + p] = t;
            tidx_w[t * 4 + (fA ? 1 : 3)] = p;
        }
        __syncthreads();
        if (tid == 0) sbase = base + tot;
        __syncthreads();
    }
    if (tid == 0) cnt[e] = sbase;
}

// helper: derive (e, off_e, cpad_e) for padded row0 from cnt[] prefix
__device__ __forceinline__ bool find_tile(const int* __restrict__ cnt,
                                          int row0, int& e, int& off_e,
                                          int& cpad_e) {
    int o = 0;
    e = -1;
#pragma unroll
    for (int q = 0; q < E_NUM; q++) {
        int c = (cnt[q] + BTM - 1) & ~(BTM - 1);
        if (row0 >= o && row0 < o + c) { e = q; off_e = o; cpad_e = c; }
        o += c;
    }
    return e >= 0;
}

// ============================ bf16 MFMA path ================================
// fc1: 128 pair-rows x 64 i (=128 f rows, g/l split tiles). BK=64 as two
// 32-wide sub-tiles. 4 waves, 2x2. grid=(32+W2X, 72).
// blockIdx.x >= 32: w2->bf16 riders (memory-only, overlap with MFMA).
__global__ __launch_bounds__(256, 3) void fc1_mfma(
    const ushort_t* __restrict__ xb, const ushort_t* __restrict__ w1b,
    const float* __restrict__ b1, const int* __restrict__ tok,
    const int* __restrict__ cnt, ushort_t* __restrict__ act,
    const float* __restrict__ w2f, ushort_t* __restrict__ w2b) {
    if (blockIdx.x >= I_DIM / 64) {
        int flat = ((int)blockIdx.x - I_DIM / 64) * TILES_Y + (int)blockIdx.y;
        int tid = (int)threadIdx.x;
        for (int c = flat; c < W2_CHUNKS; c += W2X * TILES_Y) {
            size_t g0 = (size_t)c * CHUNK_F4 + tid;
            cvt_chunk(w2f + g0 * 4, w2b + g0 * 4);
        }
        return;
    }
    int row0 = (int)blockIdx.y * BTM;
    int e, off_e, cpad_e;
    if (!find_tile(cnt, row0, e, off_e, cpad_e)) return;
    int tile = (row0 - off_e) / BTM;
    int i0 = blockIdx.x * 64;

    __shared__ ushort_t As[2][128 * 32];
    __shared__ ushort_t Bg[2][64 * 32];
    __shared__ ushort_t Bl[2][64 * 32];

    int tid = threadIdx.x;
    int lane = tid & 63;
    int ww = tid >> 6;
    int wm = ww & 1, wn = ww >> 1;
    int l15 = lane & 15, quad = lane >> 4;
    int r4 = lane >> 2;           // 0..15
    int koff = (lane & 3) * 8;    // 0,8,16,24

    const int* tlist = tok + e * T_TOK + tile * BTM;
    int ar0 = ww * 32 + r4;
    const ushort_t* a0 = xb + (size_t)tlist[ar0] * H_DIM + koff;
    const ushort_t* a1 = xb + (size_t)tlist[ar0 + 16] * H_DIM + koff;
    int il = ww * 16 + r4;
    const ushort_t* bsrc = w1b + ((size_t)e * F_DIM + 2 * (i0 + il)) * H_DIM + koff;

    ushort_t* ad0a = &As[0][(ww * 32) * 32];
    ushort_t* ad0b = &As[0][(ww * 32 + 16) * 32];
    ushort_t* ad1a = &As[1][(ww * 32) * 32];
    ushort_t* ad1b = &As[1][(ww * 32 + 16) * 32];
    ushort_t* bg0 = &Bg[0][(ww * 16) * 32];
    ushort_t* bg1 = &Bg[1][(ww * 16) * 32];
    ushort_t* bl0 = &Bl[0][(ww * 16) * 32];
    ushort_t* bl1 = &Bl[1][(ww * 16) * 32];

    f32x4 zf = {0.f, 0.f, 0.f, 0.f};
    f32x4 accg[4][2], accl[4][2];
#pragma unroll
    for (int mc = 0; mc < 4; mc++)
#pragma unroll
        for (int nc = 0; nc < 2; nc++) { accg[mc][nc] = zf; accl[mc][nc] = zf; }

    for (int k0 = 0; k0 < H_DIM; k0 += 64) {
        __syncthreads();
        gl_lds16(a0, ad0a);
        gl_lds16(a1, ad0b);
        gl_lds16(a0 + 32, ad1a);
        gl_lds16(a1 + 32, ad1b);
        gl_lds16(bsrc, bg0);
        gl_lds16(bsrc + 32, bg1);
        gl_lds16(bsrc + H_DIM, bl0);
        gl_lds16(bsrc + H_DIM + 32, bl1);
        a0 += 64; a1 += 64; bsrc += 64;
        __syncthreads();

#pragma unroll
        for (int kk = 0; kk < 2; kk++) {
            bf16x8 af[4], bgf[2], blf[2];
#pragma unroll
            for (int mc = 0; mc < 4; mc++)
                af[mc] = *(const bf16x8*)&As[kk][(wm * 64 + mc * 16 + l15) * 32 + quad * 8];
#pragma unroll
            for (int nc = 0; nc < 2; nc++) {
                bgf[nc] = *(const bf16x8*)&Bg[kk][(wn * 32 + nc * 16 + l15) * 32 + quad * 8];
                blf[nc] = *(const bf16x8*)&Bl[kk][(wn * 32 + nc * 16 + l15) * 32 + quad * 8];
            }
#pragma unroll
            for (int mc = 0; mc < 4; mc++)
#pragma unroll
                for (int nc = 0; nc < 2; nc++) {
                    accg[mc][nc] = __builtin_amdgcn_mfma_f32_16x16x32_bf16(
                        af[mc], bgf[nc], accg[mc][nc], 0, 0, 0);
                    accl[mc][nc] = __builtin_amdgcn_mfma_f32_16x16x32_bf16(
                        af[mc], blf[nc], accl[mc][nc], 0, 0, 0);
                }
        }
    }

    // epilogue: bias + swiglu (fast sigmoid), act bf16. D: row=quad*4+r, col=l15.
    int rowbase = row0 + wm * 64;
    int colbase = i0 + wn * 32;
    float bgc[2], blc[2];
#pragma unroll
    for (int nc = 0; nc < 2; nc++) {
        int i = colbase + nc * 16 + l15;
        bgc[nc] = b1[(size_t)e * F_DIM + 2 * i];
        blc[nc] = b1[(size_t)e * F_DIM + 2 * i + 1];
    }
#pragma unroll
    for (int mc = 0; mc < 4; mc++)
#pragma unroll
        for (int nc = 0; nc < 2; nc++) {
            int i = colbase + nc * 16 + l15;
#pragma unroll
            for (int r = 0; r < 4; r++) {
                int m = rowbase + mc * 16 + quad * 4 + r;
                float g = accg[mc][nc][r] + bgc[nc];
                float l = accl[mc][nc][r] + blc[nc];
                float s = __builtin_amdgcn_rcpf(
                    1.f + __builtin_amdgcn_exp2f(-ALPHA_LOG2E * g));
                act[(size_t)m * I_DIM + i] = f2bf(g * s * (l + 1.f));
            }
        }
}

// fc2: 128 pair-rows x 128 h, BK=64 split sub-tiles. grid=(16, 72).
__global__ __launch_bounds__(256, 3) void fc2_mfma(
    const ushort_t* __restrict__ act, const ushort_t* __restrict__ w2b,
    const float* __restrict__ b2, const int* __restrict__ cnt,
    ushort_t* __restrict__ ybuf) {
    int row0 = (int)blockIdx.y * BTM;
    int e, off_e, cpad_e;
    if (!find_tile(cnt, row0, e, off_e, cpad_e)) return;
    int h0 = blockIdx.x * 128;
    int rowbase = row0;

    __shared__ ushort_t As[2][128 * 32];
    __shared__ ushort_t Bs[2][128 * 32];

    int tid = threadIdx.x;
    int lane = tid & 63;
    int ww = tid >> 6;
    int wm = ww & 1, wn = ww >> 1;
    int l15 = lane & 15, quad = lane >> 4;
    int r4 = lane >> 2;
    int koff = (lane & 3) * 8;

    int ar = ww * 32 + r4;
    const ushort_t* a0 = act + (size_t)(rowbase + ar) * I_DIM + koff;
    const ushort_t* a1 = a0 + (size_t)16 * I_DIM;
    const ushort_t* b0 = w2b + ((size_t)e * H_DIM + h0 + ar) * I_DIM + koff;
    const ushort_t* b1p = b0 + (size_t)16 * I_DIM;

    ushort_t* ad0a = &As[0][(ww * 32) * 32];
    ushort_t* ad0b = &As[0][(ww * 32 + 16) * 32];
    ushort_t* ad1a = &As[1][(ww * 32) * 32];
    ushort_t* ad1b = &As[1][(ww * 32 + 16) * 32];
    ushort_t* bd0a = &Bs[0][(ww * 32) * 32];
    ushort_t* bd0b = &Bs[0][(ww * 32 + 16) * 32];
    ushort_t* bd1a = &Bs[1][(ww * 32) * 32];
    ushort_t* bd1b = &Bs[1][(ww * 32 + 16) * 32];

    f32x4 zf = {0.f, 0.f, 0.f, 0.f};
    f32x4 acc[4][4];
#pragma unroll
    for (int mc = 0; mc < 4; mc++)
#pragma unroll
        for (int nc = 0; nc < 4; nc++) acc[mc][nc] = zf;

    for (int k0 = 0; k0 < I_DIM; k0 += 64) {
        __syncthreads();
        gl_lds16(a0, ad0a);
        gl_lds16(a1, ad0b);
        gl_lds16(a0 + 32, ad1a);
        gl_lds16(a1 + 32, ad1b);
        gl_lds16(b0, bd0a);
        gl_lds16(b1p, bd0b);
        gl_lds16(b0 + 32, bd1a);
        gl_lds16(b1p + 32, bd1b);
        a0 += 64; a1 += 64; b0 += 64; b1p += 64;
        __syncthreads();

#pragma unroll
        for (int kk = 0; kk < 2; kk++) {
            bf16x8 af[4], bf[4];
#pragma unroll
            for (int mc = 0; mc < 4; mc++)
                af[mc] = *(const bf16x8*)&As[kk][(wm * 64 + mc * 16 + l15) * 32 + quad * 8];
#pragma unroll
            for (int nc = 0; nc < 4; nc++)
                bf[nc] = *(const bf16x8*)&Bs[kk][(wn * 64 + nc * 16 + l15) * 32 + quad * 8];
#pragma unroll
            for (int mc = 0; mc < 4; mc++)
#pragma unroll
                for (int nc = 0; nc < 4; nc++)
                    acc[mc][nc] = __builtin_amdgcn_mfma_f32_16x16x32_bf16(
                        af[mc], bf[nc], acc[mc][nc], 0, 0, 0);
        }
    }

    float bc[4];
#pragma unroll
    for (int nc = 0; nc < 4; nc++)
        bc[nc] = b2[(size_t)e * H_DIM + h0 + wn * 64 + nc * 16 + l15];
#pragma unroll
    for (int mc = 0; mc < 4; mc++)
#pragma unroll
        for (int nc = 0; nc < 4; nc++) {
            int h = h0 + wn * 64 + nc * 16 + l15;
#pragma unroll
            for (int r = 0; r < 4; r++) {
                int m = rowbase + wm * 64 + mc * 16 + quad * 4 + r;
                ybuf[(size_t)m * H_DIM + h] = f2bf(acc[mc][nc][r] + bc[nc]);
            }
        }
}

// combine: out[t] = w0*y[row(e0,p0)] + w1*y[row(e1,p1)]; 4 tokens per block.
__global__ __launch_bounds__(256) void combine_kernel(
    const ushort_t* __restrict__ ybuf, const int4* __restrict__ tidx,
    const float2* __restrict__ twgt, const int* __restrict__ cnt,
    float* __restrict__ out) {
    int offv[E_NUM];
    {
        int o = 0;
#pragma unroll
        for (int q = 0; q < E_NUM; q++) {
            offv[q] = o;
            o += (cnt[q] + BTM - 1) & ~(BTM - 1);
        }
    }
    int h = threadIdx.x * 8;
#pragma unroll
    for (int tt = 0; tt < 4; tt++) {
        int t = blockIdx.x * 4 + tt;
        int4 idx = tidx[t];
        float2 w = twgt[t];
        size_t r0 = (size_t)offv[idx.x] + idx.y;
        size_t r1 = (size_t)offv[idx.z] + idx.w;
        ushort8v a = *(const ushort8v*)(ybuf + r0 * H_DIM + h);
        ushort8v b = *(const ushort8v*)(ybuf + r1 * H_DIM + h);
        float* op = out + (size_t)t * H_DIM + h;
#pragma unroll
        for (int q = 0; q < 8; q++)
            op[q] = w.x * bf2f(a[q]) + w.y * bf2f(b[q]);
    }
}

// ============================ fp32 fallback path ============================
__global__ __launch_bounds__(64) void gate_fb(
    const float* __restrict__ x, const float* __restrict__ gw,
    int* __restrict__ tok, float* __restrict__ wgt,
    int4* __restrict__ tidx, float2* __restrict__ twgt, int* __restrict__ cnt) {
    int t = blockIdx.x;
    int lane = threadIdx.x;
    const float* xr = x + (size_t)t * H_DIM;
    float acc[E_NUM];
#pragma unroll
    for (int e = 0; e < E_NUM; e++) acc[e] = 0.f;
    for (int j = lane; j < H_DIM; j += 64) {
        float xv = xr[j];
#pragma unroll
        for (int e = 0; e < E_NUM; e++) acc[e] += xv * gw[e * H_DIM + j];
    }
#pragma unroll
    for (int e = 0; e < E_NUM; e++) {
#pragma unroll
        for (int s = 32; s > 0; s >>= 1) acc[e] += __shfl_xor(acc[e], s, 64);
    }
    if (lane == 0) {
        int i0 = 0; float b0 = acc[0];
        for (int e = 1; e < E_NUM; e++) if (acc[e] > b0) { b0 = acc[e]; i0 = e; }
        int i1 = -1; float b1 = -3.0e38f;
        for (int e = 0; e < E_NUM; e++) {
            if (e == i0) continue;
            if (acc[e] > b1) { b1 = acc[e]; i1 = e; }
        }
        float e10 = expf(b1 - b0);
        float w0 = 1.f / (1.f + e10);
        float w1 = 1.f - w0;
        int p0 = atomicAdd(&cnt[i0], 1);
        tok[i0 * T_TOK + p0] = t; wgt[i0 * T_TOK + p0] = w0;
        int p1 = atomicAdd(&cnt[i1], 1);
        tok[i1 * T_TOK + p1] = t; wgt[i1 * T_TOK + p1] = w1;
        tidx[t] = make_int4(i0, p0, i1, p1);
        twgt[t] = make_float2(w0, w1);
    }
}

__global__ __launch_bounds__(256) void pad_kernel(
    int* __restrict__ tok, float* __restrict__ wgt,
    const int* __restrict__ cnt, int* __restrict__ cnt_pad,
    int* __restrict__ off, int tile) {
    __shared__ int s_cnt[E_NUM], s_pad[E_NUM];
    if (threadIdx.x == 0) {
        int o = 0;
        for (int e = 0; e < E_NUM; e++) {
            int c = cnt[e];
            int cp = (c + tile - 1) / tile * tile;
            s_cnt[e] = c; s_pad[e] = cp;
            cnt_pad[e] = cp;
            off[e] = o;
            o += cp;
        }
    }
    __syncthreads();
    for (int e = 0; e < E_NUM; e++) {
        for (int p = s_cnt[e] + (int)threadIdx.x; p < s_pad[e]; p += 256) {
            tok[e * T_TOK + p] = 0;
            wgt[e * T_TOK + p] = 0.f;
        }
    }
}

__global__ __launch_bounds__(256) void fc1_kernel(
    const float* __restrict__ x, const float* __restrict__ w1,
    const float* __restrict__ b1, const int* __restrict__ tok,
    const int* __restrict__ cnt_pad, const int* __restrict__ off,
    ushort_t* __restrict__ act) {
    int e = blockIdx.y >> 6;
    int tile = blockIdx.y & 63;
    if (tile * TILE_M >= cnt_pad[e]) return;
    int i0 = blockIdx.x * 64;
    int f0 = i0 * 2;

    __shared__ float xs[KT][TILE_M + 4];
    __shared__ float wsh[KT][128 + 4];

    int tid = threadIdx.x;
    int tx = tid & 15, ty = tid >> 4;
    int rloc = tid >> 3;
    int c4 = (tid & 7) * 4;

    const int* tlist = tok + e * T_TOK + tile * TILE_M;
    int tk0 = tlist[rloc];
    int tk1 = tlist[rloc + 32];
    const float* xp0 = x + (size_t)tk0 * H_DIM + c4;
    const float* xp1 = x + (size_t)tk1 * H_DIM + c4;
    const float* wp = w1 + ((size_t)e * F_DIM + f0 + rloc) * H_DIM + c4;

    float ga[4][4] = {{0.f}}, la[4][4] = {{0.f}};

    for (int k0 = 0; k0 < H_DIM; k0 += KT) {
        __syncthreads();
        {
            float4 v0 = *(const float4*)(xp0 + k0);
            float4 v1 = *(const float4*)(xp1 + k0);
            xs[c4 + 0][rloc] = v0.x; xs[c4 + 1][rloc] = v0.y;
            xs[c4 + 2][rloc] = v0.z; xs[c4 + 3][rloc] = v0.w;
            xs[c4 + 0][rloc + 32] = v1.x; xs[c4 + 1][rloc + 32] = v1.y;
            xs[c4 + 2][rloc + 32] = v1.z; xs[c4 + 3][rloc + 32] = v1.w;
        }
        {
#pragma unroll
            for (int r = 0; r < 4; r++) {
                float4 v = *(const float4*)(wp + (size_t)(32 * r) * H_DIM + k0);
                int fr = rloc + 32 * r;
                wsh[c4 + 0][fr] = v.x; wsh[c4 + 1][fr] = v.y;
                wsh[c4 + 2][fr] = v.z; wsh[c4 + 3][fr] = v.w;
            }
        }
        __syncthreads();
#pragma unroll
        for (int k = 0; k < KT; k++) {
            float4 xv = *(const float4*)&xs[k][ty * 4];
            float4 wa = *(const float4*)&wsh[k][tx * 8];
            float4 wb = *(const float4*)&wsh[k][tx * 8 + 4];
            float xm[4] = {xv.x, xv.y, xv.z, xv.w};
            float gg[4] = {wa.x, wa.z, wb.x, wb.z};
            float ll[4] = {wa.y, wa.w, wb.y, wb.w};
#pragma unroll
            for (int m = 0; m < 4; m++)
#pragma unroll
                for (int n = 0; n < 4; n++) {
                    ga[m][n] += xm[m] * gg[n];
                    la[m][n] += xm[m] * ll[n];
                }
        }
    }

    int rowbase = off[e] + tile * TILE_M;
    float bg[4], bl[4];
#pragma unroll
    for (int n = 0; n < 4; n++) {
        int i = i0 + tx * 4 + n;
        bg[n] = b1[(size_t)e * F_DIM + 2 * i];
        bl[n] = b1[(size_t)e * F_DIM + 2 * i + 1];
    }
#pragma unroll
    for (int m = 0; m < 4; m++) {
        int row = rowbase + ty * 4 + m;
        ushort_t us[4];
#pragma unroll
        for (int n = 0; n < 4; n++) {
            float g = ga[m][n] + bg[n];
            float l = la[m][n] + bl[n];
            float s = 1.f / (1.f + expf(-ALPHA_C * g));
            us[n] = f2bf(g * s * (l + 1.f));
        }
        *(ushort4*)&act[(size_t)row * I_DIM + i0 + tx * 4] =
            make_ushort4(us[0], us[1], us[2], us[3]);
    }
}

__global__ __launch_bounds__(256) void fc2_kernel(
    const ushort_t* __restrict__ act, const float* __restrict__ w2,
    const float* __restrict__ b2, const int* __restrict__ tok,
    const float* __restrict__ wgt, const int* __restrict__ cnt_pad,
    const int* __restrict__ off, float* __restrict__ out) {
    int e = blockIdx.y >> 6;
    int tile = blockIdx.y & 63;
    if (tile * TILE_M >= cnt_pad[e]) return;
    int h0 = blockIdx.x * 64;

    __shared__ float as_[KT][TILE_M + 4];
    __shared__ float wsh[KT][64 + 4];

    int tid = threadIdx.x;
    int tx = tid & 15, ty = tid >> 4;
    int rowbase = off[e] + tile * TILE_M;

    int arow = tid >> 2;
    int ac8 = (tid & 3) * 8;
    const ushort_t* ap = act + (size_t)(rowbase + arow) * I_DIM + ac8;
    int rloc = tid >> 3;
    int c4 = (tid & 7) * 4;
    const float* wp = w2 + ((size_t)e * H_DIM + h0 + rloc) * I_DIM + c4;

    float acc[4][4] = {{0.f}};

    for (int k0 = 0; k0 < I_DIM; k0 += KT) {
        __syncthreads();
        {
            ushort8v v = *(const ushort8v*)(ap + k0);
#pragma unroll
            for (int q = 0; q < 8; q++) as_[ac8 + q][arow] = bf2f(v[q]);
        }
        {
#pragma unroll
            for (int r = 0; r < 2; r++) {
                float4 v = *(const float4*)(wp + (size_t)(32 * r) * I_DIM + k0);
                int hr = rloc + 32 * r;
                wsh[c4 + 0][hr] = v.x; wsh[c4 + 1][hr] = v.y;
                wsh[c4 + 2][hr] = v.z; wsh[c4 + 3][hr] = v.w;
            }
        }
        __syncthreads();
#pragma unroll
        for (int k = 0; k < KT; k++) {
            float4 xv = *(const float4*)&as_[k][ty * 4];
            float4 wv = *(const float4*)&wsh[k][tx * 4];
            float xm[4] = {xv.x, xv.y, xv.z, xv.w};
            float wn[4] = {wv.x, wv.y, wv.z, wv.w};
#pragma unroll
            for (int m = 0; m < 4; m++)
#pragma unroll
                for (int n = 0; n < 4; n++) acc[m][n] += xm[m] * wn[n];
        }
    }

    const int* tlist = tok + e * T_TOK + tile * TILE_M;
    const float* wlist = wgt + e * T_TOK + tile * TILE_M;
#pragma unroll
    for (int m = 0; m < 4; m++) {
        int row = ty * 4 + m;
        int t = tlist[row];
        float w = wlist[row];
        if (w == 0.f) continue;
#pragma unroll
        for (int n = 0; n < 4; n++) {
            int h = h0 + tx * 4 + n;
            float y = acc[m][n] + b2[(size_t)e * H_DIM + h];
            atomicAdd(out + (size_t)t * H_DIM + h, w * y);
        }
    }
}

// --------------------------------------------------------------- launch -----
extern "C" void kernel_launch(void* const* d_in, const int* in_sizes, int n_in,
                              void* d_out, int out_size, void* d_ws, size_t ws_size,
                              hipStream_t stream) {
    const float* x  = (const float*)d_in[0];
    const float* gw = (const float*)d_in[1];
    const float* w1 = (const float*)d_in[2];
    const float* b1 = (const float*)d_in[3];
    const float* w2 = (const float*)d_in[4];
    const float* b2 = (const float*)d_in[5];
    float* out = (float*)d_out;
    char* ws = (char*)d_ws;

    size_t w1b_sz = (size_t)E_NUM * F_DIM * H_DIM * 2;  // 134217728
    size_t w2b_sz = (size_t)E_NUM * H_DIM * I_DIM * 2;  // 67108864
    size_t xb_sz  = (size_t)T_TOK * H_DIM * 2;          // 16777216
    size_t act_sz = (size_t)ACT_CAP_B * I_DIM * 2;      // 37748736
    size_t tok_sz = (size_t)E_NUM * T_TOK * 4;          // 131072
    size_t tidx_sz = (size_t)T_TOK * 16;
    size_t twgt_sz = (size_t)T_TOK * 8;
    size_t need_big = w1b_sz + w2b_sz + xb_sz + act_sz + tok_sz + 64 +
                      tidx_sz + twgt_sz + 256;

    if (ws_size >= need_big) {
        ushort_t* w1b = (ushort_t*)ws;                       // also ybuf later
        ushort_t* w2b = (ushort_t*)(ws + w1b_sz);
        ushort_t* xb  = (ushort_t*)(ws + w1b_sz + w2b_sz);
        ushort_t* act = (ushort_t*)(ws + w1b_sz + w2b_sz + xb_sz);
        char* p = ws + w1b_sz + w2b_sz + xb_sz + act_sz;
        int*    tok  = (int*)p;                 p += tok_sz;
        int*    cnt  = (int*)p;                 p += 64;   // adjacent to tok
        int4*   tidx = (int4*)p;                p += tidx_sz;
        float2* twgt = (float2*)p;
        ushort_t* ybuf = w1b;   // w1b dead after fc1

        // zero tok lists (+cnt region): padding = token 0 for free
        hipMemsetAsync(tok, 0, tok_sz + 64, stream);
        gate_kernel<<<GATE_BLOCKS + CVT1_BLOCKS, 256, 0, stream>>>(
            x, gw, w1, w1b, xb, tidx, twgt);
        route_kernel<<<E_NUM, 256, 0, stream>>>(
            (const int4*)tidx, (int*)tidx, tok, cnt);
        fc1_mfma<<<dim3(I_DIM / 64 + W2X, TILES_Y), 256, 0, stream>>>(
            xb, w1b, b1, tok, cnt, act, w2, w2b);
        fc2_mfma<<<dim3(H_DIM / 128, TILES_Y), 256, 0, stream>>>(
            act, w2b, b2, cnt, ybuf);
        combine_kernel<<<T_TOK / 4, 256, 0, stream>>>(ybuf, tidx, twgt, cnt, out);
        return;
    }

    // fp32 fallback (round-1 proven)
    size_t actB = (size_t)ACT_CAP_F * I_DIM * 2;
    ushort_t* act = (ushort_t*)ws;
    char* p = ws + actB;
    int*    tok  = (int*)p;     p += tok_sz;
    float*  wgt  = (float*)p;   p += tok_sz;
    int4*   tidx = (int4*)p;    p += tidx_sz;
    float2* twgt = (float2*)p;  p += twgt_sz;
    int*    cnt  = (int*)p;
    int*    cnt_pad = cnt + E_NUM;
    int*    off  = cnt_pad + E_NUM;
    size_t need = actB + 2 * tok_sz + tidx_sz + twgt_sz + 256;
    if (ws_size < need) return;

    hipMemsetAsync(cnt, 0, E_NUM * sizeof(int), stream);
    hipMemsetAsync(d_out, 0, (size_t)T_TOK * H_DIM * sizeof(float), stream);
    gate_fb<<<T_TOK, 64, 0, stream>>>(x, gw, tok, wgt, tidx, twgt, cnt);
    pad_kernel<<<1, 256, 0, stream>>>(tok, wgt, cnt, cnt_pad, off, TILE_M);
    fc1_kernel<<<dim3(I_DIM / 64, E_NUM * 64), 256, 0, stream>>>(
        x, w1, b1, tok, cnt_pad, off, act);
    fc2_kernel<<<dim3(H_DIM / 64, E_NUM * 64), 256, 0, stream>>>(
        act, w2, b2, tok, wgt, cnt_pad, off, out);
}